// Round 5
// baseline (378.140 us; speedup 1.0000x reference)
//
#include <hip/hip_runtime.h>
#include <hip/hip_bf16.h>
#include <stdint.h>

#define DEVI __device__ __forceinline__

typedef __attribute__((ext_vector_type(8))) short bf16x8;    // 8 bf16 (4 VGPRs)
typedef __attribute__((ext_vector_type(4))) float f32x4;     // 4 fp32 acc
typedef __attribute__((ext_vector_type(16))) float f32x16;   // 16 fp32 acc (32x32 MFMA)

// Problem constants: B=2, S=8192, D=2048, H=16, hd=128, SEG=512, DIL=2
//   -> n_seg=16, L=256, M = B*16*256 = 8192 rows, E3 = 6144.

DEVI unsigned short f2bf(float f) {               // RNE float->bf16
  unsigned int u = __float_as_uint(f);
  return (unsigned short)((u + 0x7fffu + ((u >> 16) & 1u)) >> 16);
}

DEVI void load_lds16(const void* g, void* l) {    // async global->LDS, 16B/lane
  __builtin_amdgcn_global_load_lds(
      (const __attribute__((address_space(1))) unsigned int*)g,
      (__attribute__((address_space(3))) unsigned int*)l, 16, 0, 0);
}

DEVI bf16x8 ld8(const unsigned short* p) {
  return *reinterpret_cast<const bf16x8*>(p);
}

// ---------------- prep: dilated gather + cast x -> bf16 ----------------
__global__ void k_gather(const float* __restrict__ x, unsigned short* __restrict__ xs) {
  int i = blockIdx.x * 256 + threadIdx.x;      // one float4 per thread; 4194304 total
  int r = i >> 9;                              // out row 0..8191
  int c = (i & 511) << 2;                      // col element
  int b = r >> 12;
  int rem = r & 4095;
  int seg = rem >> 8;
  int lcl = rem & 255;
  long src_row = (long)b * 8192 + seg * 512 + lcl * 2;   // dilation=2
  const float4 v = *reinterpret_cast<const float4*>(x + src_row * 2048 + c);
  uint2 o;
  o.x = f2bf(v.x) | ((unsigned)f2bf(v.y) << 16);
  o.y = f2bf(v.z) | ((unsigned)f2bf(v.w) << 16);
  *reinterpret_cast<uint2*>(xs + (long)r * 2048 + c) = o;
}

__global__ void k_cast(const float* __restrict__ in, unsigned short* __restrict__ out, int n4) {
  int i = blockIdx.x * 256 + threadIdx.x;
  if (i >= n4) return;
  const float4 v = *reinterpret_cast<const float4*>(in + (long)i * 4);
  uint2 o;
  o.x = f2bf(v.x) | ((unsigned)f2bf(v.y) << 16);
  o.y = f2bf(v.z) | ((unsigned)f2bf(v.w) << 16);
  *reinterpret_cast<uint2*>(out + (long)i * 4) = o;
}

// ---------------- GEMM: C[M,N] = A[M,K] * B[N,K]^T + bias ----------------
// 256x256 tile, BK=32, 8 waves (2M x 4N, 128x64 each), 4-buffer LDS ring
// (4 x 32KB), counted vmcnt(8) pipeline (2 tiles in flight, never drains in
// main loop), raw s_barrier, setprio around MFMA clusters.
// MFMA shape: 32x32x16 (2x FLOP per instruction at same fragment bytes;
// halves MFMA issue slots, +15% pipe rate vs 16x16x32).
// LDS layout: PAIR-PACKED 128B rows (conflict-free): logical rows (2p,2p+1)
// share physical row p; chunk c=(r&1)*4+(k>>3), swizzled cs=c^(p&7).
// Inverse swizzle folded into per-lane global source (gload_lds rule).

DEVI unsigned short* lds_of(unsigned short* smem, int tile, int op) {
  return smem + (tile & 3) * 16384 + op * 8192;    // op: 0=A, 1=B (16KB each)
}

DEVI void stage_op(const unsigned short* gb, int K, int kt,
                   unsigned short* region, int t, int w) {
#pragma unroll
  for (int i = 0; i < 2; ++i) {
    int s = i * 512 + t;                       // 16B slot 0..1023
    int prow = s >> 3;                         // physical row 0..127
    int cs = s & 7;                            // swizzled chunk
    int c = cs ^ (prow & 7);                   // logical chunk
    int r = prow * 2 + (c >> 2);               // logical row 0..255
    int k0 = (c & 3) << 3;                     // k element offset
    load_lds16(gb + (long)r * K + kt * 32 + k0,
               (char*)region + i * 8192 + w * 1024);
  }
}

// 32x32x16 fragment reads. A: row = wm*128 + mm*32 + (l&31),
// k-chunk ck = ks*2 + (l>>5); B: row = wn*64 + nn*32 + (l&31).
#define FRAG_A(dst, mm, ks)                                                  \
  { int r_ = wm * 128 + (mm) * 32 + l31;                                     \
    int p_ = r_ >> 1;                                                        \
    int cs_ = (((r_ & 1) << 2) | ((ks) * 2 + lh)) ^ (p_ & 7);                \
    dst = ld8(Ab_ + p_ * 64 + cs_ * 8); }
#define FRAG_B(dst, nn, ks)                                                  \
  { int r_ = wn * 64 + (nn) * 32 + l31;                                      \
    int p_ = r_ >> 1;                                                        \
    int cs_ = (((r_ & 1) << 2) | ((ks) * 2 + lh)) ^ (p_ & 7);                \
    dst = ld8(Bb_ + p_ * 64 + cs_ * 8); }
#define MM(mm, areg)                                                         \
  acc[mm][0] = __builtin_amdgcn_mfma_f32_32x32x16_bf16(areg, bf0, acc[mm][0], 0, 0, 0); \
  acc[mm][1] = __builtin_amdgcn_mfma_f32_32x32x16_bf16(areg, bf1, acc[mm][1], 0, 0, 0);

// One K-tile (BK=32): vmcnt(VM) -> barrier -> stage A(j+3) -> frags ks=0
// -> 8 MFMA -> stage B(j+3) -> mid barrier -> frags ks=1 -> 8 MFMA.
#define TILE(JEXPR, VMLIT, DOSTAGE)                                          \
  {                                                                          \
    const int j_ = (JEXPR);                                                  \
    asm volatile("s_waitcnt vmcnt(" VMLIT ")" ::: "memory");                 \
    __builtin_amdgcn_s_barrier();                                            \
    asm volatile("" ::: "memory");                                           \
    __builtin_amdgcn_sched_barrier(0);                                       \
    const unsigned short* Ab_ = smem + (j_ & 3) * 16384;                     \
    const unsigned short* Bb_ = Ab_ + 8192;                                  \
    if (DOSTAGE) stage_op(Agb, K, j_ + 3, lds_of(smem, j_ + 3, 0), t, w);    \
    bf16x8 af0, af1, af2, af3, bf0, bf1;                                     \
    FRAG_B(bf0, 0, 0) FRAG_B(bf1, 1, 0)                                      \
    FRAG_A(af0, 0, 0) FRAG_A(af1, 1, 0) FRAG_A(af2, 2, 0) FRAG_A(af3, 3, 0)  \
    __builtin_amdgcn_s_setprio(1);                                           \
    MM(0, af0) MM(1, af1) MM(2, af2) MM(3, af3)                              \
    __builtin_amdgcn_s_setprio(0);                                           \
    if (DOSTAGE) stage_op(Bgb, K, j_ + 3, lds_of(smem, j_ + 3, 1), t, w);    \
    __builtin_amdgcn_s_barrier();                                            \
    asm volatile("" ::: "memory");                                           \
    FRAG_B(bf0, 0, 1) FRAG_B(bf1, 1, 1)                                      \
    FRAG_A(af0, 0, 1) FRAG_A(af1, 1, 1) FRAG_A(af2, 2, 1) FRAG_A(af3, 3, 1)  \
    __builtin_amdgcn_s_setprio(1);                                           \
    MM(0, af0) MM(1, af1) MM(2, af2) MM(3, af3)                              \
    __builtin_amdgcn_s_setprio(0);                                           \
  }

template <bool BF16_OUT>
__global__ __launch_bounds__(512, 1)
void k_gemm(const unsigned short* __restrict__ A, const unsigned short* __restrict__ B,
            const float* __restrict__ bias, void* __restrict__ Cv, int N, int K) {
  __shared__ unsigned short smem[65536];       // 128 KB: 4 bufs x (A 16KB + B 16KB)
  const int nbx = N >> 8;
  const int cpx = gridDim.x >> 3;              // grid % 8 == 0 (bijective XCD swizzle)
  const int id = blockIdx.x;
  const int sw = (id & 7) * cpx + (id >> 3);
  const int bx = sw % nbx, by = sw / nbx;
  const int t = threadIdx.x, w = t >> 6, l = t & 63;
  const int l31 = l & 31, lh = l >> 5;
  const int wm = w >> 2, wn = w & 3;
  const unsigned short* Agb = A + (long)by * 256 * K;
  const unsigned short* Bgb = B + (long)bx * 256 * K;
  const int nk = K >> 5;                       // 64 for K=2048
  f32x16 acc[4][2] = {};

  // prologue: stage tiles 0,1,2 (12 loads/thread)
  for (int jt = 0; jt < 3; ++jt) {
    stage_op(Agb, K, jt, lds_of(smem, jt, 0), t, w);
    stage_op(Bgb, K, jt, lds_of(smem, jt, 1), t, w);
  }
  // main loop: vmcnt(8) keeps tiles j+1, j+2 (4 loads each) in flight
  for (int j = 0; j < nk - 3; ++j) TILE(j, "8", true)
  TILE(nk - 3, "8", false)
  TILE(nk - 2, "4", false)
  TILE(nk - 1, "0", false)

  // epilogue: bias + store.
  // 32x32 C/D layout: col = lane&31, row = (reg&3) + 8*(reg>>2) + 4*(lane>>5)
  const long crow0 = (long)by * 256 + wm * 128;
  const int ccol0 = bx * 256 + wn * 64;
#pragma unroll
  for (int nn = 0; nn < 2; ++nn) {
    int col = ccol0 + nn * 32 + l31;
    float bv = bias[col];
#pragma unroll
    for (int mm = 0; mm < 4; ++mm) {
      long rbase = crow0 + mm * 32 + lh * 4;
#pragma unroll
      for (int reg = 0; reg < 16; ++reg) {
        long r_g = rbase + (reg & 3) + 8 * (reg >> 2);
        float v = acc[mm][nn][reg] + bv;
        if (BF16_OUT)
          ((unsigned short*)Cv)[r_g * N + col] = f2bf(v);
        else
          ((float*)Cv)[r_g * N + col] = v;
      }
    }
  }
}

// ---------------- fused per-(b,n,h) attention ----------------
// 1 block = 1 (b,n,h): 8 waves x 32 q-rows. K,Vt staged in LDS (swizzled),
// full 256-wide scores per wave in registers, wave-parallel softmax,
// P -> per-wave LDS region (reusing K space) -> PV MFMA.
__global__ __launch_bounds__(512)
void k_attn(const unsigned short* __restrict__ qkv, unsigned short* __restrict__ aout) {
  __shared__ unsigned short smem[65536];    // 128KB
  unsigned short* Kl = smem;                // [256][128] bf16, chunk ^= row&7; reused as P
  unsigned short* Vt = smem + 32768;        // [128][256] bf16 (d-major), chunk ^= (d^(d>>3))&7
  const int p = blockIdx.x;
  const int h = p & 15;
  const long rb = (long)(p >> 4) * 256;
  const int t = threadIdx.x, w = t >> 6, l = t & 63;
  const int lr = l & 15, lq = l >> 4;

  // --- stage K via global_load_lds with pre-swizzled source
  const unsigned short* kb = qkv + rb * 6144 + 2048 + h * 128;
#pragma unroll
  for (int i = 0; i < 8; ++i) {
    int s = i * 512 + t;
    int row = s >> 4;
    int ch = (s & 15) ^ (row & 7);
    load_lds16(kb + (long)row * 6144 + ch * 8, (char*)Kl + i * 8192 + w * 1024);
  }
  // --- stage V transposed (reg path; swizzled scatter writes, ~2-way conflicts)
  const unsigned short* vb = qkv + rb * 6144 + 4096 + h * 128;
#pragma unroll
  for (int j0 = 0; j0 < 8; ++j0) {
    int k = j0 * 32 + (t >> 4);
    int d0 = (t & 15) * 8;
    bf16x8 v = ld8(vb + (long)k * 6144 + d0);
#pragma unroll
    for (int j = 0; j < 8; ++j) {
      int d = d0 + j;
      int ch = (k >> 3) ^ ((d ^ (d >> 3)) & 7);
      Vt[d * 256 + ch * 8 + (k & 7)] = (unsigned short)(short)v[j];
    }
  }
  // --- Q fragments straight from global
  const unsigned short* qb = qkv + (rb + w * 32) * 6144 + h * 128;
  bf16x8 qa[2][4];
#pragma unroll
  for (int m = 0; m < 2; ++m)
#pragma unroll
    for (int kt = 0; kt < 4; ++kt)
      qa[m][kt] = ld8(qb + (long)(m * 16 + lr) * 6144 + kt * 32 + lq * 8);

  __syncthreads();

  // --- S = Q K^T : per wave 32x256 in registers
  f32x4 sacc[2][16] = {};
#pragma unroll
  for (int n = 0; n < 16; ++n) {
    int row = n * 16 + lr;
#pragma unroll
    for (int kt = 0; kt < 4; ++kt) {
      int ch = (kt * 4 + lq) ^ (row & 7);
      bf16x8 kf = ld8(Kl + row * 128 + ch * 8);
      sacc[0][n] = __builtin_amdgcn_mfma_f32_16x16x32_bf16(qa[0][kt], kf, sacc[0][n], 0, 0, 0);
      sacc[1][n] = __builtin_amdgcn_mfma_f32_16x16x32_bf16(qa[1][kt], kf, sacc[1][n], 0, 0, 0);
    }
  }
  // --- softmax(scale*S) rowwise; row = m*16+lq*4+r, col spread over n and lane&15
  const float scale = 0.08838834764831845f;  // 1/sqrt(128)
  float mx[2][4], sm[2][4];
#pragma unroll
  for (int m = 0; m < 2; ++m)
#pragma unroll
    for (int r = 0; r < 4; ++r) {
      float v = sacc[m][0][r];
#pragma unroll
      for (int n = 1; n < 16; ++n) v = fmaxf(v, sacc[m][n][r]);
      mx[m][r] = v;
      sm[m][r] = 0.f;
    }
#pragma unroll
  for (int mk = 1; mk < 16; mk <<= 1)
#pragma unroll
    for (int m = 0; m < 2; ++m)
#pragma unroll
      for (int r = 0; r < 4; ++r)
        mx[m][r] = fmaxf(mx[m][r], __shfl_xor(mx[m][r], mk));
#pragma unroll
  for (int m = 0; m < 2; ++m)
#pragma unroll
    for (int n = 0; n < 16; ++n)
#pragma unroll
      for (int r = 0; r < 4; ++r) {
        float e = __expf((sacc[m][n][r] - mx[m][r]) * scale);
        sacc[m][n][r] = e;
        sm[m][r] += e;
      }
#pragma unroll
  for (int mk = 1; mk < 16; mk <<= 1)
#pragma unroll
    for (int m = 0; m < 2; ++m)
#pragma unroll
      for (int r = 0; r < 4; ++r)
        sm[m][r] += __shfl_xor(sm[m][r], mk);
  float ri[2][4];
#pragma unroll
  for (int m = 0; m < 2; ++m)
#pragma unroll
    for (int r = 0; r < 4; ++r) ri[m][r] = 1.0f / sm[m][r];

  // --- normalize + pack P to bf16 pairs (frees the 128 f32 sacc regs)
  unsigned int pb[2][16][2];
#pragma unroll
  for (int m = 0; m < 2; ++m)
#pragma unroll
    for (int n = 0; n < 16; ++n) {
      pb[m][n][0] = f2bf(sacc[m][n][0] * ri[m][0]) | ((unsigned)f2bf(sacc[m][n][1] * ri[m][1]) << 16);
      pb[m][n][1] = f2bf(sacc[m][n][2] * ri[m][2]) | ((unsigned)f2bf(sacc[m][n][3] * ri[m][3]) << 16);
    }

  __syncthreads();                       // all waves done reading Kl -> reuse as P
  unsigned short* Pl = Kl + w * 4096;    // per-wave 8KB: [32][128] bf16, chunk ^= row&7
  f32x4 oacc[2][8] = {};
#pragma unroll
  for (int half = 0; half < 2; ++half) {
#pragma unroll
    for (int m = 0; m < 2; ++m)
#pragma unroll
      for (int n = 0; n < 8; ++n) {
        int col = n * 16 + lr;
        int row0 = m * 16 + lq * 4;
#pragma unroll
        for (int pr = 0; pr < 2; ++pr) {
          unsigned int u = pb[m][half * 8 + n][pr];
          int ra = row0 + pr * 2, rbw = ra + 1;
          int ca = (col >> 3) ^ (ra & 7);
          int cb = (col >> 3) ^ (rbw & 7);
          Pl[ra * 128 + ca * 8 + (col & 7)] = (unsigned short)(u & 0xffffu);
          Pl[rbw * 128 + cb * 8 + (col & 7)] = (unsigned short)(u >> 16);
        }
      }
    // O += P V  (A-frags from Pl, B-frags from swizzled Vt)
#pragma unroll
    for (int kt = 0; kt < 4; ++kt) {
      bf16x8 pa[2];
#pragma unroll
      for (int m = 0; m < 2; ++m) {
        int row = m * 16 + lr;
        int ch = (kt * 4 + lq) ^ (row & 7);
        pa[m] = ld8(Pl + row * 128 + ch * 8);
      }
#pragma unroll
      for (int dt = 0; dt < 8; ++dt) {
        int d = dt * 16 + lr;
        int kg = half * 128 + kt * 32 + lq * 8;
        int ch = (kg >> 3) ^ ((d ^ (d >> 3)) & 7);
        bf16x8 vf = ld8(Vt + d * 256 + ch * 8);
        oacc[0][dt] = __builtin_amdgcn_mfma_f32_16x16x32_bf16(pa[0], vf, oacc[0][dt], 0, 0, 0);
        oacc[1][dt] = __builtin_amdgcn_mfma_f32_16x16x32_bf16(pa[1], vf, oacc[1][dt], 0, 0, 0);
      }
    }
  }
  // --- write O (bf16) at [row, h*128 + d]
  unsigned short* ob = aout + (rb + w * 32) * 2048 + h * 128;
#pragma unroll
  for (int m = 0; m < 2; ++m)
#pragma unroll
    for (int dt = 0; dt < 8; ++dt)
#pragma unroll
      for (int r = 0; r < 4; ++r)
        ob[(long)(m * 16 + lq * 4 + r) * 2048 + dt * 16 + lr] = f2bf(oacc[m][dt][r]);
}

// ---------------- launch ----------------
extern "C" void kernel_launch(void* const* d_in, const int* in_sizes, int n_in,
                              void* d_out, int out_size, void* d_ws, size_t ws_size,
                              hipStream_t stream) {
  const float* x     = (const float*)d_in[0];
  const float* Wqkv  = (const float*)d_in[1];
  const float* b_qkv = (const float*)d_in[2];
  const float* Wout  = (const float*)d_in[3];
  const float* b_out = (const float*)d_in[4];
  float* out = (float*)d_out;

  char* ws = (char*)d_ws;
  // workspace layout (160 MiB total); aout aliases xs (xs dead after GEMM1)
  unsigned short* xs   = (unsigned short*)(ws);                 // 33,554,432 B
  unsigned short* aout = xs;                                    // alias
  unsigned short* wq   = (unsigned short*)(ws + 33554432);      // 25,165,824 B
  unsigned short* wo   = (unsigned short*)(ws + 58720256);      //  8,388,608 B
  unsigned short* qkv  = (unsigned short*)(ws + 67108864);      // 100,663,296 B

  k_gather<<<16384, 256, 0, stream>>>(x, xs);
  k_cast<<<12288, 256, 0, stream>>>(Wqkv, wq, 3145728);
  k_cast<<<4096, 256, 0, stream>>>(Wout, wo, 1048576);
  // QKV projection: [8192,2048] x [6144,2048]^T -> bf16 [8192,6144]
  k_gemm<true><<<32 * 24, 512, 0, stream>>>(xs, wq, b_qkv, (void*)qkv, 6144, 2048);
  // 512 fused attentions
  k_attn<<<512, 512, 0, stream>>>(qkv, aout);
  // out projection: [8192,2048] x [2048,2048]^T -> f32 d_out
  k_gemm<false><<<32 * 8, 512, 0, stream>>>(aout, wo, b_out, (void*)out, 2048, 2048);
}

// Round 6
// 370.833 us; speedup vs baseline: 1.0197x; 1.0197x over previous
//
#include <hip/hip_runtime.h>
#include <hip/hip_bf16.h>
#include <stdint.h>

#define DEVI __device__ __forceinline__

typedef __attribute__((ext_vector_type(8))) short bf16x8;   // 8 bf16 (4 VGPRs)
typedef __attribute__((ext_vector_type(4))) float f32x4;    // 4 fp32 acc

// Problem constants: B=2, S=8192, D=2048, H=16, hd=128, SEG=512, DIL=2
//   -> n_seg=16, L=256, M = B*16*256 = 8192 rows, E3 = 6144.

DEVI unsigned short f2bf(float f) {               // RNE float->bf16
  unsigned int u = __float_as_uint(f);
  return (unsigned short)((u + 0x7fffu + ((u >> 16) & 1u)) >> 16);
}

DEVI void load_lds16(const void* g, void* l) {    // async global->LDS, 16B/lane
  __builtin_amdgcn_global_load_lds(
      (const __attribute__((address_space(1))) unsigned int*)g,
      (__attribute__((address_space(3))) unsigned int*)l, 16, 0, 0);
}

DEVI bf16x8 ld8(const unsigned short* p) {
  return *reinterpret_cast<const bf16x8*>(p);
}

// ---------------- prep: dilated gather + cast x -> bf16 ----------------
__global__ void k_gather(const float* __restrict__ x, unsigned short* __restrict__ xs) {
  int i = blockIdx.x * 256 + threadIdx.x;      // one float4 per thread; 4194304 total
  int r = i >> 9;                              // out row 0..8191
  int c = (i & 511) << 2;                      // col element
  int b = r >> 12;
  int rem = r & 4095;
  int seg = rem >> 8;
  int lcl = rem & 255;
  long src_row = (long)b * 8192 + seg * 512 + lcl * 2;   // dilation=2
  const float4 v = *reinterpret_cast<const float4*>(x + src_row * 2048 + c);
  uint2 o;
  o.x = f2bf(v.x) | ((unsigned)f2bf(v.y) << 16);
  o.y = f2bf(v.z) | ((unsigned)f2bf(v.w) << 16);
  *reinterpret_cast<uint2*>(xs + (long)r * 2048 + c) = o;
}

__global__ void k_cast(const float* __restrict__ in, unsigned short* __restrict__ out, int n4) {
  int i = blockIdx.x * 256 + threadIdx.x;
  if (i >= n4) return;
  const float4 v = *reinterpret_cast<const float4*>(in + (long)i * 4);
  uint2 o;
  o.x = f2bf(v.x) | ((unsigned)f2bf(v.y) << 16);
  o.y = f2bf(v.z) | ((unsigned)f2bf(v.w) << 16);
  *reinterpret_cast<uint2*>(out + (long)i * 4) = o;
}

// ---------------- GEMM: C[M,N] = A[M,K] * B[N,K]^T + bias ----------------
// 256x256 tile, BK=64, 8 waves (2M x 4N, 128x64 each), classic double buffer
// (2 x 64KB), all 8 stage-loads for tile j+1 issued at tile-j start (slack =
// full tile >= HBM latency, so the per-tile vmcnt(0) drain is stall-free).
// Per K-tile: 4 phases {ds_read frags -> barrier -> lgkmcnt(0)+sched_barrier
// -> setprio(1) 16 MFMA setprio(0) -> barrier}; B-frags of each K-half are
// reused across the two row-half phases.
// LDS layout: natural 128B rows (64 bf16), chunk swizzle ch = c ^ (row&7)
// (round-1-verified 0 bank conflicts). Inverse swizzle folded into per-lane
// global source; each 8-lane staging group reads a CONTIGUOUS 128B row
// segment (coalesced), fixing rounds 2-5's scattered-source staging.

DEVI void stage_piece(const unsigned short* gb, int K, int kt, int h,
                      unsigned short* opbuf, int t, int w) {
#pragma unroll
  for (int i = 0; i < 2; ++i) {
    int s = i * 512 + t;                       // 16B slot 0..1023 within piece
    int lrow = s >> 3;                         // 0..127 (row within half)
    int cs = s & 7;                            // physical chunk
    int c = cs ^ (lrow & 7);                   // logical chunk (inv swizzle)
    load_lds16(gb + (long)(h * 128 + lrow) * K + kt * 64 + c * 8,
               (char*)opbuf + h * 16384 + i * 8192 + w * 1024);
  }
}

#define FRAG_A(dst, mm, kk)                                                  \
  { int r_ = wm * 128 + (mm) * 16 + lr;                                      \
    int ch_ = ((kk) * 4 + lq) ^ (r_ & 7);                                    \
    dst = ld8(Ab_ + r_ * 64 + ch_ * 8); }
#define FRAG_B(dst, nn, kk)                                                  \
  { int r_ = wn * 64 + (nn) * 16 + lr;                                       \
    int ch_ = ((kk) * 4 + lq) ^ (r_ & 7);                                    \
    dst = ld8(Bb_ + r_ * 64 + ch_ * 8); }
#define MM(mm, areg)                                                         \
  acc[mm][0] = __builtin_amdgcn_mfma_f32_16x16x32_bf16(areg, bf0, acc[mm][0], 0, 0, 0); \
  acc[mm][1] = __builtin_amdgcn_mfma_f32_16x16x32_bf16(areg, bf1, acc[mm][1], 0, 0, 0); \
  acc[mm][2] = __builtin_amdgcn_mfma_f32_16x16x32_bf16(areg, bf2, acc[mm][2], 0, 0, 0); \
  acc[mm][3] = __builtin_amdgcn_mfma_f32_16x16x32_bf16(areg, bf3, acc[mm][3], 0, 0, 0);

#define PHASE_MM(m0, m1, m2, m3)                                             \
    __builtin_amdgcn_s_barrier();                                            \
    asm volatile("s_waitcnt lgkmcnt(0)" ::: "memory");                       \
    __builtin_amdgcn_sched_barrier(0);                                       \
    __builtin_amdgcn_s_setprio(1);                                           \
    MM(m0, af0) MM(m1, af1) MM(m2, af2) MM(m3, af3)                          \
    __builtin_amdgcn_s_setprio(0);                                           \
    __builtin_amdgcn_s_barrier();                                            \
    asm volatile("" ::: "memory");

#define PHASE_MM_LAST(m0, m1, m2, m3)                                        \
    __builtin_amdgcn_s_barrier();                                            \
    asm volatile("s_waitcnt lgkmcnt(0)" ::: "memory");                       \
    __builtin_amdgcn_sched_barrier(0);                                       \
    __builtin_amdgcn_s_setprio(1);                                           \
    MM(m0, af0) MM(m1, af1) MM(m2, af2) MM(m3, af3)                          \
    __builtin_amdgcn_s_setprio(0);                                           \
    asm volatile("s_waitcnt vmcnt(0)" ::: "memory");                         \
    __builtin_amdgcn_s_barrier();                                            \
    asm volatile("" ::: "memory");

// One K-tile (BK=64): stage tile j+1 (8 coalesced gloads), then 4 phases.
#define TILE64(JEXPR, DOSTAGE)                                               \
  {                                                                          \
    const int j_ = (JEXPR);                                                  \
    const unsigned short* Ab_ = smem + (j_ & 1) * 32768;                     \
    const unsigned short* Bb_ = Ab_ + 16384;                                 \
    unsigned short* An_ = smem + ((j_ + 1) & 1) * 32768;                     \
    unsigned short* Bn_ = An_ + 16384;                                       \
    if (DOSTAGE) {                                                           \
      stage_piece(Agb, K, j_ + 1, 0, An_, t, w);                             \
      stage_piece(Bgb, K, j_ + 1, 0, Bn_, t, w);                             \
      stage_piece(Agb, K, j_ + 1, 1, An_, t, w);                             \
      stage_piece(Bgb, K, j_ + 1, 1, Bn_, t, w);                             \
    }                                                                        \
    bf16x8 af0, af1, af2, af3, bf0, bf1, bf2, bf3;                           \
    FRAG_B(bf0, 0, 0) FRAG_B(bf1, 1, 0) FRAG_B(bf2, 2, 0) FRAG_B(bf3, 3, 0)  \
    FRAG_A(af0, 0, 0) FRAG_A(af1, 1, 0) FRAG_A(af2, 2, 0) FRAG_A(af3, 3, 0)  \
    PHASE_MM(0, 1, 2, 3)                                                     \
    FRAG_A(af0, 4, 0) FRAG_A(af1, 5, 0) FRAG_A(af2, 6, 0) FRAG_A(af3, 7, 0)  \
    PHASE_MM(4, 5, 6, 7)                                                     \
    FRAG_B(bf0, 0, 1) FRAG_B(bf1, 1, 1) FRAG_B(bf2, 2, 1) FRAG_B(bf3, 3, 1)  \
    FRAG_A(af0, 0, 1) FRAG_A(af1, 1, 1) FRAG_A(af2, 2, 1) FRAG_A(af3, 3, 1)  \
    PHASE_MM(0, 1, 2, 3)                                                     \
    FRAG_A(af0, 4, 1) FRAG_A(af1, 5, 1) FRAG_A(af2, 6, 1) FRAG_A(af3, 7, 1)  \
    PHASE_MM_LAST(4, 5, 6, 7)                                                \
  }

template <bool BF16_OUT>
__global__ __launch_bounds__(512, 1)
void k_gemm(const unsigned short* __restrict__ A, const unsigned short* __restrict__ B,
            const float* __restrict__ bias, void* __restrict__ Cv, int N, int K) {
  __shared__ unsigned short smem[65536];       // 128 KB: 2 bufs x (A 32KB + B 32KB)
  const int nbx = N >> 8;
  const int cpx = gridDim.x >> 3;              // grid % 8 == 0 (bijective XCD swizzle)
  const int id = blockIdx.x;
  const int sw = (id & 7) * cpx + (id >> 3);
  const int bx = sw % nbx, by = sw / nbx;
  const int t = threadIdx.x, w = t >> 6, l = t & 63;
  const int lr = l & 15, lq = l >> 4;
  const int wm = w >> 2, wn = w & 3;
  const unsigned short* Agb = A + (long)by * 256 * K;
  const unsigned short* Bgb = B + (long)bx * 256 * K;
  const int nk = K >> 6;                       // 32 for K=2048
  f32x4 acc[8][4] = {};

  // prologue: stage tile 0 into buf0, drain, barrier
  stage_piece(Agb, K, 0, 0, smem, t, w);
  stage_piece(Bgb, K, 0, 0, smem + 16384, t, w);
  stage_piece(Agb, K, 0, 1, smem, t, w);
  stage_piece(Bgb, K, 0, 1, smem + 16384, t, w);
  asm volatile("s_waitcnt vmcnt(0)" ::: "memory");
  __builtin_amdgcn_s_barrier();
  asm volatile("" ::: "memory");

  for (int j = 0; j < nk - 1; ++j) TILE64(j, true)
  TILE64(nk - 1, false)

  // epilogue: bias + store. C/D layout: col=lane&15, row=(lane>>4)*4+reg
  const long crow0 = (long)by * 256 + wm * 128;
  const int ccol0 = bx * 256 + wn * 64;
#pragma unroll
  for (int n = 0; n < 4; ++n) {
    int col = ccol0 + n * 16 + lr;
    float bv = bias[col];
#pragma unroll
    for (int m = 0; m < 8; ++m) {
      long r0 = crow0 + m * 16 + lq * 4;
#pragma unroll
      for (int r = 0; r < 4; ++r) {
        float v = acc[m][n][r] + bv;
        if (BF16_OUT)
          ((unsigned short*)Cv)[(r0 + r) * N + col] = f2bf(v);
        else
          ((float*)Cv)[(r0 + r) * N + col] = v;
      }
    }
  }
}

// ---------------- fused per-(b,n,h) attention ----------------
// 1 block = 1 (b,n,h): 8 waves x 32 q-rows. K,Vt staged in LDS (swizzled),
// full 256-wide scores per wave in registers, wave-parallel softmax,
// P -> per-wave LDS region (reusing K space) -> PV MFMA.
__global__ __launch_bounds__(512)
void k_attn(const unsigned short* __restrict__ qkv, unsigned short* __restrict__ aout) {
  __shared__ unsigned short smem[65536];    // 128KB
  unsigned short* Kl = smem;                // [256][128] bf16, chunk ^= row&7; reused as P
  unsigned short* Vt = smem + 32768;        // [128][256] bf16 (d-major), chunk ^= (d^(d>>3))&7
  const int p = blockIdx.x;
  const int h = p & 15;
  const long rb = (long)(p >> 4) * 256;
  const int t = threadIdx.x, w = t >> 6, l = t & 63;
  const int lr = l & 15, lq = l >> 4;

  // --- stage K via global_load_lds with pre-swizzled source
  const unsigned short* kb = qkv + rb * 6144 + 2048 + h * 128;
#pragma unroll
  for (int i = 0; i < 8; ++i) {
    int s = i * 512 + t;
    int row = s >> 4;
    int ch = (s & 15) ^ (row & 7);
    load_lds16(kb + (long)row * 6144 + ch * 8, (char*)Kl + i * 8192 + w * 1024);
  }
  // --- stage V transposed (reg path; swizzled scatter writes, ~2-way conflicts)
  const unsigned short* vb = qkv + rb * 6144 + 4096 + h * 128;
#pragma unroll
  for (int j0 = 0; j0 < 8; ++j0) {
    int k = j0 * 32 + (t >> 4);
    int d0 = (t & 15) * 8;
    bf16x8 v = ld8(vb + (long)k * 6144 + d0);
#pragma unroll
    for (int j = 0; j < 8; ++j) {
      int d = d0 + j;
      int ch = (k >> 3) ^ ((d ^ (d >> 3)) & 7);
      Vt[d * 256 + ch * 8 + (k & 7)] = (unsigned short)(short)v[j];
    }
  }
  // --- Q fragments straight from global
  const unsigned short* qb = qkv + (rb + w * 32) * 6144 + h * 128;
  bf16x8 qa[2][4];
#pragma unroll
  for (int m = 0; m < 2; ++m)
#pragma unroll
    for (int kt = 0; kt < 4; ++kt)
      qa[m][kt] = ld8(qb + (long)(m * 16 + lr) * 6144 + kt * 32 + lq * 8);

  __syncthreads();

  // --- S = Q K^T : per wave 32x256 in registers
  f32x4 sacc[2][16] = {};
#pragma unroll
  for (int n = 0; n < 16; ++n) {
    int row = n * 16 + lr;
#pragma unroll
    for (int kt = 0; kt < 4; ++kt) {
      int ch = (kt * 4 + lq) ^ (row & 7);
      bf16x8 kf = ld8(Kl + row * 128 + ch * 8);
      sacc[0][n] = __builtin_amdgcn_mfma_f32_16x16x32_bf16(qa[0][kt], kf, sacc[0][n], 0, 0, 0);
      sacc[1][n] = __builtin_amdgcn_mfma_f32_16x16x32_bf16(qa[1][kt], kf, sacc[1][n], 0, 0, 0);
    }
  }
  // --- softmax(scale*S) rowwise; row = m*16+lq*4+r, col spread over n and lane&15
  const float scale = 0.08838834764831845f;  // 1/sqrt(128)
  float mx[2][4], sm[2][4];
#pragma unroll
  for (int m = 0; m < 2; ++m)
#pragma unroll
    for (int r = 0; r < 4; ++r) {
      float v = sacc[m][0][r];
#pragma unroll
      for (int n = 1; n < 16; ++n) v = fmaxf(v, sacc[m][n][r]);
      mx[m][r] = v;
      sm[m][r] = 0.f;
    }
#pragma unroll
  for (int mk = 1; mk < 16; mk <<= 1)
#pragma unroll
    for (int m = 0; m < 2; ++m)
#pragma unroll
      for (int r = 0; r < 4; ++r)
        mx[m][r] = fmaxf(mx[m][r], __shfl_xor(mx[m][r], mk));
#pragma unroll
  for (int m = 0; m < 2; ++m)
#pragma unroll
    for (int n = 0; n < 16; ++n)
#pragma unroll
      for (int r = 0; r < 4; ++r) {
        float e = __expf((sacc[m][n][r] - mx[m][r]) * scale);
        sacc[m][n][r] = e;
        sm[m][r] += e;
      }
#pragma unroll
  for (int mk = 1; mk < 16; mk <<= 1)
#pragma unroll
    for (int m = 0; m < 2; ++m)
#pragma unroll
      for (int r = 0; r < 4; ++r)
        sm[m][r] += __shfl_xor(sm[m][r], mk);
  float ri[2][4];
#pragma unroll
  for (int m = 0; m < 2; ++m)
#pragma unroll
    for (int r = 0; r < 4; ++r) ri[m][r] = 1.0f / sm[m][r];

  // --- normalize + pack P to bf16 pairs (frees the 128 f32 sacc regs)
  unsigned int pb[2][16][2];
#pragma unroll
  for (int m = 0; m < 2; ++m)
#pragma unroll
    for (int n = 0; n < 16; ++n) {
      pb[m][n][0] = f2bf(sacc[m][n][0] * ri[m][0]) | ((unsigned)f2bf(sacc[m][n][1] * ri[m][1]) << 16);
      pb[m][n][1] = f2bf(sacc[m][n][2] * ri[m][2]) | ((unsigned)f2bf(sacc[m][n][3] * ri[m][3]) << 16);
    }

  __syncthreads();                       // all waves done reading Kl -> reuse as P
  unsigned short* Pl = Kl + w * 4096;    // per-wave 8KB: [32][128] bf16, chunk ^= row&7
  f32x4 oacc[2][8] = {};
#pragma unroll
  for (int half = 0; half < 2; ++half) {
#pragma unroll
    for (int m = 0; m < 2; ++m)
#pragma unroll
      for (int n = 0; n < 8; ++n) {
        int col = n * 16 + lr;
        int row0 = m * 16 + lq * 4;
#pragma unroll
        for (int pr = 0; pr < 2; ++pr) {
          unsigned int u = pb[m][half * 8 + n][pr];
          int ra = row0 + pr * 2, rbw = ra + 1;
          int ca = (col >> 3) ^ (ra & 7);
          int cb = (col >> 3) ^ (rbw & 7);
          Pl[ra * 128 + ca * 8 + (col & 7)] = (unsigned short)(u & 0xffffu);
          Pl[rbw * 128 + cb * 8 + (col & 7)] = (unsigned short)(u >> 16);
        }
      }
    // O += P V  (A-frags from Pl, B-frags from swizzled Vt)
#pragma unroll
    for (int kt = 0; kt < 4; ++kt) {
      bf16x8 pa[2];
#pragma unroll
      for (int m = 0; m < 2; ++m) {
        int row = m * 16 + lr;
        int ch = (kt * 4 + lq) ^ (row & 7);
        pa[m] = ld8(Pl + row * 128 + ch * 8);
      }
#pragma unroll
      for (int dt = 0; dt < 8; ++dt) {
        int d = dt * 16 + lr;
        int kg = half * 128 + kt * 32 + lq * 8;
        int ch = (kg >> 3) ^ ((d ^ (d >> 3)) & 7);
        bf16x8 vf = ld8(Vt + d * 256 + ch * 8);
        oacc[0][dt] = __builtin_amdgcn_mfma_f32_16x16x32_bf16(pa[0], vf, oacc[0][dt], 0, 0, 0);
        oacc[1][dt] = __builtin_amdgcn_mfma_f32_16x16x32_bf16(pa[1], vf, oacc[1][dt], 0, 0, 0);
      }
    }
  }
  // --- write O (bf16) at [row, h*128 + d]
  unsigned short* ob = aout + (rb + w * 32) * 2048 + h * 128;
#pragma unroll
  for (int m = 0; m < 2; ++m)
#pragma unroll
    for (int dt = 0; dt < 8; ++dt)
#pragma unroll
      for (int r = 0; r < 4; ++r)
        ob[(long)(m * 16 + lq * 4 + r) * 2048 + dt * 16 + lr] = f2bf(oacc[m][dt][r]);
}

// ---------------- launch ----------------
extern "C" void kernel_launch(void* const* d_in, const int* in_sizes, int n_in,
                              void* d_out, int out_size, void* d_ws, size_t ws_size,
                              hipStream_t stream) {
  const float* x     = (const float*)d_in[0];
  const float* Wqkv  = (const float*)d_in[1];
  const float* b_qkv = (const float*)d_in[2];
  const float* Wout  = (const float*)d_in[3];
  const float* b_out = (const float*)d_in[4];
  float* out = (float*)d_out;

  char* ws = (char*)d_ws;
  // workspace layout (160 MiB total); aout aliases xs (xs dead after GEMM1)
  unsigned short* xs   = (unsigned short*)(ws);                 // 33,554,432 B
  unsigned short* aout = xs;                                    // alias
  unsigned short* wq   = (unsigned short*)(ws + 33554432);      // 25,165,824 B
  unsigned short* wo   = (unsigned short*)(ws + 58720256);      //  8,388,608 B
  unsigned short* qkv  = (unsigned short*)(ws + 67108864);      // 100,663,296 B

  k_gather<<<16384, 256, 0, stream>>>(x, xs);
  k_cast<<<12288, 256, 0, stream>>>(Wqkv, wq, 3145728);
  k_cast<<<4096, 256, 0, stream>>>(Wout, wo, 1048576);
  // QKV projection: [8192,2048] x [6144,2048]^T -> bf16 [8192,6144]
  k_gemm<true><<<32 * 24, 512, 0, stream>>>(xs, wq, b_qkv, (void*)qkv, 6144, 2048);
  // 512 fused attentions
  k_attn<<<512, 512, 0, stream>>>(qkv, aout);
  // out projection: [8192,2048] x [2048,2048]^T -> f32 d_out
  k_gemm<false><<<32 * 8, 512, 0, stream>>>(aout, wo, b_out, (void*)out, 2048, 2048);
}

// Round 7
// 354.284 us; speedup vs baseline: 1.0673x; 1.0467x over previous
//
#include <hip/hip_runtime.h>
#include <hip/hip_bf16.h>
#include <stdint.h>

#define DEVI __device__ __forceinline__

typedef __attribute__((ext_vector_type(8))) short bf16x8;   // 8 bf16 (4 VGPRs)
typedef __attribute__((ext_vector_type(4))) float f32x4;    // 4 fp32 acc

// Problem constants: B=2, S=8192, D=2048, H=16, hd=128, SEG=512, DIL=2
//   -> n_seg=16, L=256, M = B*16*256 = 8192 rows, E3 = 6144.

DEVI unsigned short f2bf(float f) {               // RNE float->bf16
  unsigned int u = __float_as_uint(f);
  return (unsigned short)((u + 0x7fffu + ((u >> 16) & 1u)) >> 16);
}

DEVI void load_lds16(const void* g, void* l) {    // async global->LDS, 16B/lane
  __builtin_amdgcn_global_load_lds(
      (const __attribute__((address_space(1))) unsigned int*)g,
      (__attribute__((address_space(3))) unsigned int*)l, 16, 0, 0);
}

DEVI bf16x8 ld8(const unsigned short* p) {
  return *reinterpret_cast<const bf16x8*>(p);
}

// ---------------- prep: dilated gather + cast x -> bf16 ----------------
__global__ void k_gather(const float* __restrict__ x, unsigned short* __restrict__ xs) {
  int i = blockIdx.x * 256 + threadIdx.x;      // one float4 per thread; 4194304 total
  int r = i >> 9;                              // out row 0..8191
  int c = (i & 511) << 2;                      // col element
  int b = r >> 12;
  int rem = r & 4095;
  int seg = rem >> 8;
  int lcl = rem & 255;
  long src_row = (long)b * 8192 + seg * 512 + lcl * 2;   // dilation=2
  const float4 v = *reinterpret_cast<const float4*>(x + src_row * 2048 + c);
  uint2 o;
  o.x = f2bf(v.x) | ((unsigned)f2bf(v.y) << 16);
  o.y = f2bf(v.z) | ((unsigned)f2bf(v.w) << 16);
  *reinterpret_cast<uint2*>(xs + (long)r * 2048 + c) = o;
}

__global__ void k_cast(const float* __restrict__ in, unsigned short* __restrict__ out, int n4) {
  int i = blockIdx.x * 256 + threadIdx.x;
  if (i >= n4) return;
  const float4 v = *reinterpret_cast<const float4*>(in + (long)i * 4);
  uint2 o;
  o.x = f2bf(v.x) | ((unsigned)f2bf(v.y) << 16);
  o.y = f2bf(v.z) | ((unsigned)f2bf(v.w) << 16);
  *reinterpret_cast<uint2*>(out + (long)i * 4) = o;
}

// ---------------- GEMM: C[M,N] = A[M,K] * B[N,K]^T + bias ----------------
// 256x256 tile, 8 waves (2M x 4N, 128x64 each). K processed in K-HALVES of
// 32; LDS = ring of 4 slots x 32KB (A-piece 16KB + B-piece 16KB per half).
// Pipeline: while computing half h (from slot h&3), stage half h+2 (A piece
// in phase alpha, B piece in phase beta). Trailing vmcnt(4) per half drains
// exactly half h+1's 4 loads (never 0 in main loop); issue->need slack for a
// half is ~4 phases (~600-800 cy), covering HBM latency.
// Per half, 2 phases: {ds_read frags | stage piece | barrier | lgkmcnt(0) |
// setprio(1) 16 MFMA setprio(0) | barrier}.
// LDS layout: pair-packed 128B rows (round-3-verified 0 bank conflicts):
// logical (r,k): prow=r>>1, c8=(r&1)*4+(k>>3), swizzled cs8=c8^(prow&7).
// Inverse swizzle folded into per-lane global source (gload_lds rule).
// Epilogue: per-wave LDS transpose -> b128 coalesced stores (64B segments).

DEVI void stage_piece(const unsigned short* gb, int K, int h, int op,
                      unsigned short* smem, int t, int w) {
  char* base = (char*)(smem + (h & 3) * 16384 + op * 8192);
#pragma unroll
  for (int i = 0; i < 2; ++i) {
    int s = i * 512 + t;                       // 16B slot 0..1023
    int prow = s >> 3;                         // 0..127
    int cs8 = s & 7;
    int c8 = cs8 ^ (prow & 7);
    int r = prow * 2 + (c8 >> 2);              // logical row 0..255
    int k0 = (c8 & 3) << 3;                    // k element 0/8/16/24
    load_lds16(gb + (long)r * K + h * 32 + k0, base + i * 8192 + w * 1024);
  }
}

#define FRAG_A(dst, mm)                                                      \
  { int r_ = wm * 128 + (mm) * 16 + lr;                                      \
    int p_ = r_ >> 1;                                                        \
    int cs_ = (((r_ & 1) << 2) | lq) ^ (p_ & 7);                             \
    dst = ld8(Ab_ + p_ * 64 + cs_ * 8); }
#define FRAG_B(dst, nn)                                                      \
  { int r_ = wn * 64 + (nn) * 16 + lr;                                       \
    int p_ = r_ >> 1;                                                        \
    int cs_ = (((r_ & 1) << 2) | lq) ^ (p_ & 7);                             \
    dst = ld8(Bb_ + p_ * 64 + cs_ * 8); }
#define MM(mm, areg)                                                         \
  acc[mm][0] = __builtin_amdgcn_mfma_f32_16x16x32_bf16(areg, bf0, acc[mm][0], 0, 0, 0); \
  acc[mm][1] = __builtin_amdgcn_mfma_f32_16x16x32_bf16(areg, bf1, acc[mm][1], 0, 0, 0); \
  acc[mm][2] = __builtin_amdgcn_mfma_f32_16x16x32_bf16(areg, bf2, acc[mm][2], 0, 0, 0); \
  acc[mm][3] = __builtin_amdgcn_mfma_f32_16x16x32_bf16(areg, bf3, acc[mm][3], 0, 0, 0);

// One K-half (32 wide): phase alpha computes m0-3 x n0-3, beta m4-7 x n0-3.
#define HALF(HEXPR, DOSTAGE, VMLIT)                                          \
  {                                                                          \
    const int h_ = (HEXPR);                                                  \
    const unsigned short* Ab_ = smem + (h_ & 3) * 16384;                     \
    const unsigned short* Bb_ = Ab_ + 8192;                                  \
    bf16x8 af0, af1, af2, af3, bf0, bf1, bf2, bf3;                           \
    FRAG_B(bf0, 0) FRAG_B(bf1, 1) FRAG_B(bf2, 2) FRAG_B(bf3, 3)              \
    FRAG_A(af0, 0) FRAG_A(af1, 1) FRAG_A(af2, 2) FRAG_A(af3, 3)              \
    if (DOSTAGE) stage_piece(Agb, K, h_ + 2, 0, smem, t, w);                 \
    __builtin_amdgcn_s_barrier();                                            \
    asm volatile("s_waitcnt lgkmcnt(0)" ::: "memory");                       \
    __builtin_amdgcn_sched_barrier(0);                                       \
    __builtin_amdgcn_s_setprio(1);                                           \
    MM(0, af0) MM(1, af1) MM(2, af2) MM(3, af3)                              \
    __builtin_amdgcn_s_setprio(0);                                           \
    __builtin_amdgcn_s_barrier();                                            \
    FRAG_A(af0, 4) FRAG_A(af1, 5) FRAG_A(af2, 6) FRAG_A(af3, 7)              \
    if (DOSTAGE) stage_piece(Bgb, K, h_ + 2, 1, smem, t, w);                 \
    __builtin_amdgcn_s_barrier();                                            \
    asm volatile("s_waitcnt lgkmcnt(0)" ::: "memory");                       \
    __builtin_amdgcn_sched_barrier(0);                                       \
    __builtin_amdgcn_s_setprio(1);                                           \
    MM(4, af0) MM(5, af1) MM(6, af2) MM(7, af3)                              \
    __builtin_amdgcn_s_setprio(0);                                           \
    asm volatile("s_waitcnt vmcnt(" VMLIT ")" ::: "memory");                 \
    __builtin_amdgcn_s_barrier();                                            \
  }

template <bool BF16_OUT>
__global__ __launch_bounds__(512, 1)
void k_gemm(const unsigned short* __restrict__ A, const unsigned short* __restrict__ B,
            const float* __restrict__ bias, void* __restrict__ Cv, int N, int K) {
  __shared__ unsigned short smem[65536];       // 128 KB: 4 slots x 32KB
  const int nbx = N >> 8;
  const int cpx = gridDim.x >> 3;              // grid % 8 == 0 (bijective XCD swizzle)
  const int id = blockIdx.x;
  const int sw = (id & 7) * cpx + (id >> 3);
  const int bx = sw % nbx, by = sw / nbx;
  const int t = threadIdx.x, w = t >> 6, l = t & 63;
  const int lr = l & 15, lq = l >> 4;
  const int wm = w >> 2, wn = w & 3;
  const unsigned short* Agb = A + (long)by * 256 * K;
  const unsigned short* Bgb = B + (long)bx * 256 * K;
  const int nh = K >> 5;                       // 64 halves for K=2048
  f32x4 acc[8][4] = {};

  // prologue: stage halves 0 and 1 (8 loads/thread), need half 0 -> vmcnt(4)
  stage_piece(Agb, K, 0, 0, smem, t, w);
  stage_piece(Bgb, K, 0, 1, smem, t, w);
  stage_piece(Agb, K, 1, 0, smem, t, w);
  stage_piece(Bgb, K, 1, 1, smem, t, w);
  asm volatile("s_waitcnt vmcnt(4)" ::: "memory");
  __builtin_amdgcn_s_barrier();

  // main loop: trailing vmcnt(4) drains half h+1, leaves half h+2 in flight
  for (int h = 0; h < nh - 2; ++h) HALF(h, true, "4")
  HALF(nh - 2, false, "0")
  HALF(nh - 1, false, "0")

  // ---- epilogue: per-wave LDS transpose -> coalesced b128 stores ----
  const long crow0 = (long)by * 256 + wm * 128;
  const int ccol0 = bx * 256 + wn * 64;
  float bv[4];
#pragma unroll
  for (int n = 0; n < 4; ++n) bv[n] = bias[ccol0 + n * 16 + lr];
  const int lrr = l >> 2;                      // 0..15 readback row
  if (BF16_OUT) {
    unsigned short* Lw = smem + w * 1216;      // 16 rows x stride 76 bf16
    const int lcb = (l & 3) * 8;
#pragma unroll
    for (int m = 0; m < 8; ++m) {
#pragma unroll
      for (int n = 0; n < 4; ++n)
#pragma unroll
        for (int r = 0; r < 4; ++r)
          Lw[(lq * 4 + r) * 76 + n * 16 + lr] = f2bf(acc[m][n][r] + bv[n]);
      asm volatile("s_waitcnt lgkmcnt(0)" ::: "memory");
#pragma unroll
      for (int rd = 0; rd < 2; ++rd) {
        bf16x8 v = ld8(Lw + lrr * 76 + lcb + rd * 32);
        *reinterpret_cast<bf16x8*>((unsigned short*)Cv +
            (crow0 + m * 16 + lrr) * N + ccol0 + lcb + rd * 32) = v;
      }
    }
  } else {
    float* Lf = (float*)smem + w * 1216;       // 16 rows x stride 76 f32
    const int lcf = (l & 3) * 4;
#pragma unroll
    for (int m = 0; m < 8; ++m) {
#pragma unroll
      for (int n = 0; n < 4; ++n)
#pragma unroll
        for (int r = 0; r < 4; ++r)
          Lf[(lq * 4 + r) * 76 + n * 16 + lr] = acc[m][n][r] + bv[n];
      asm volatile("s_waitcnt lgkmcnt(0)" ::: "memory");
#pragma unroll
      for (int rd = 0; rd < 4; ++rd) {
        float4 v = *reinterpret_cast<const float4*>(Lf + lrr * 76 + lcf + rd * 16);
        *reinterpret_cast<float4*>((float*)Cv +
            (crow0 + m * 16 + lrr) * N + ccol0 + lcf + rd * 16) = v;
      }
    }
  }
}

// ---------------- fused per-(b,n,h) attention ----------------
// 1 block = 1 (b,n,h): 8 waves x 32 q-rows. K,Vt staged in LDS (swizzled),
// full 256-wide scores per wave in registers, wave-parallel softmax,
// P -> per-wave LDS region (reusing K space) -> PV MFMA.
__global__ __launch_bounds__(512)
void k_attn(const unsigned short* __restrict__ qkv, unsigned short* __restrict__ aout) {
  __shared__ unsigned short smem[65536];    // 128KB
  unsigned short* Kl = smem;                // [256][128] bf16, chunk ^= row&7; reused as P
  unsigned short* Vt = smem + 32768;        // [128][256] bf16 (d-major), chunk ^= (d^(d>>3))&7
  const int p = blockIdx.x;
  const int h = p & 15;
  const long rb = (long)(p >> 4) * 256;
  const int t = threadIdx.x, w = t >> 6, l = t & 63;
  const int lr = l & 15, lq = l >> 4;

  // --- stage K via global_load_lds with pre-swizzled source
  const unsigned short* kb = qkv + rb * 6144 + 2048 + h * 128;
#pragma unroll
  for (int i = 0; i < 8; ++i) {
    int s = i * 512 + t;
    int row = s >> 4;
    int ch = (s & 15) ^ (row & 7);
    load_lds16(kb + (long)row * 6144 + ch * 8, (char*)Kl + i * 8192 + w * 1024);
  }
  // --- stage V transposed (reg path; swizzled scatter writes, ~2-way conflicts)
  const unsigned short* vb = qkv + rb * 6144 + 4096 + h * 128;
#pragma unroll
  for (int j0 = 0; j0 < 8; ++j0) {
    int k = j0 * 32 + (t >> 4);
    int d0 = (t & 15) * 8;
    bf16x8 v = ld8(vb + (long)k * 6144 + d0);
#pragma unroll
    for (int j = 0; j < 8; ++j) {
      int d = d0 + j;
      int ch = (k >> 3) ^ ((d ^ (d >> 3)) & 7);
      Vt[d * 256 + ch * 8 + (k & 7)] = (unsigned short)(short)v[j];
    }
  }
  // --- Q fragments straight from global
  const unsigned short* qb = qkv + (rb + w * 32) * 6144 + h * 128;
  bf16x8 qa[2][4];
#pragma unroll
  for (int m = 0; m < 2; ++m)
#pragma unroll
    for (int kt = 0; kt < 4; ++kt)
      qa[m][kt] = ld8(qb + (long)(m * 16 + lr) * 6144 + kt * 32 + lq * 8);

  __syncthreads();

  // --- S = Q K^T : per wave 32x256 in registers
  f32x4 sacc[2][16] = {};
#pragma unroll
  for (int n = 0; n < 16; ++n) {
    int row = n * 16 + lr;
#pragma unroll
    for (int kt = 0; kt < 4; ++kt) {
      int ch = (kt * 4 + lq) ^ (row & 7);
      bf16x8 kf = ld8(Kl + row * 128 + ch * 8);
      sacc[0][n] = __builtin_amdgcn_mfma_f32_16x16x32_bf16(qa[0][kt], kf, sacc[0][n], 0, 0, 0);
      sacc[1][n] = __builtin_amdgcn_mfma_f32_16x16x32_bf16(qa[1][kt], kf, sacc[1][n], 0, 0, 0);
    }
  }
  // --- softmax(scale*S) rowwise; row = m*16+lq*4+r, col spread over n and lane&15
  const float scale = 0.08838834764831845f;  // 1/sqrt(128)
  float mx[2][4], sm[2][4];
#pragma unroll
  for (int m = 0; m < 2; ++m)
#pragma unroll
    for (int r = 0; r < 4; ++r) {
      float v = sacc[m][0][r];
#pragma unroll
      for (int n = 1; n < 16; ++n) v = fmaxf(v, sacc[m][n][r]);
      mx[m][r] = v;
      sm[m][r] = 0.f;
    }
#pragma unroll
  for (int mk = 1; mk < 16; mk <<= 1)
#pragma unroll
    for (int m = 0; m < 2; ++m)
#pragma unroll
      for (int r = 0; r < 4; ++r)
        mx[m][r] = fmaxf(mx[m][r], __shfl_xor(mx[m][r], mk));
#pragma unroll
  for (int m = 0; m < 2; ++m)
#pragma unroll
    for (int n = 0; n < 16; ++n)
#pragma unroll
      for (int r = 0; r < 4; ++r) {
        float e = __expf((sacc[m][n][r] - mx[m][r]) * scale);
        sacc[m][n][r] = e;
        sm[m][r] += e;
      }
#pragma unroll
  for (int mk = 1; mk < 16; mk <<= 1)
#pragma unroll
    for (int m = 0; m < 2; ++m)
#pragma unroll
      for (int r = 0; r < 4; ++r)
        sm[m][r] += __shfl_xor(sm[m][r], mk);
  float ri[2][4];
#pragma unroll
  for (int m = 0; m < 2; ++m)
#pragma unroll
    for (int r = 0; r < 4; ++r) ri[m][r] = 1.0f / sm[m][r];

  // --- normalize + pack P to bf16 pairs (frees the 128 f32 sacc regs)
  unsigned int pb[2][16][2];
#pragma unroll
  for (int m = 0; m < 2; ++m)
#pragma unroll
    for (int n = 0; n < 16; ++n) {
      pb[m][n][0] = f2bf(sacc[m][n][0] * ri[m][0]) | ((unsigned)f2bf(sacc[m][n][1] * ri[m][1]) << 16);
      pb[m][n][1] = f2bf(sacc[m][n][2] * ri[m][2]) | ((unsigned)f2bf(sacc[m][n][3] * ri[m][3]) << 16);
    }

  __syncthreads();                       // all waves done reading Kl -> reuse as P
  unsigned short* Pl = Kl + w * 4096;    // per-wave 8KB: [32][128] bf16, chunk ^= row&7
  f32x4 oacc[2][8] = {};
#pragma unroll
  for (int half = 0; half < 2; ++half) {
#pragma unroll
    for (int m = 0; m < 2; ++m)
#pragma unroll
      for (int n = 0; n < 8; ++n) {
        int col = n * 16 + lr;
        int row0 = m * 16 + lq * 4;
#pragma unroll
        for (int pr = 0; pr < 2; ++pr) {
          unsigned int u = pb[m][half * 8 + n][pr];
          int ra = row0 + pr * 2, rbw = ra + 1;
          int ca = (col >> 3) ^ (ra & 7);
          int cb = (col >> 3) ^ (rbw & 7);
          Pl[ra * 128 + ca * 8 + (col & 7)] = (unsigned short)(u & 0xffffu);
          Pl[rbw * 128 + cb * 8 + (col & 7)] = (unsigned short)(u >> 16);
        }
      }
    // O += P V  (A-frags from Pl, B-frags from swizzled Vt)
#pragma unroll
    for (int kt = 0; kt < 4; ++kt) {
      bf16x8 pa[2];
#pragma unroll
      for (int m = 0; m < 2; ++m) {
        int row = m * 16 + lr;
        int ch = (kt * 4 + lq) ^ (row & 7);
        pa[m] = ld8(Pl + row * 128 + ch * 8);
      }
#pragma unroll
      for (int dt = 0; dt < 8; ++dt) {
        int d = dt * 16 + lr;
        int kg = half * 128 + kt * 32 + lq * 8;
        int ch = (kg >> 3) ^ ((d ^ (d >> 3)) & 7);
        bf16x8 vf = ld8(Vt + d * 256 + ch * 8);
        oacc[0][dt] = __builtin_amdgcn_mfma_f32_16x16x32_bf16(pa[0], vf, oacc[0][dt], 0, 0, 0);
        oacc[1][dt] = __builtin_amdgcn_mfma_f32_16x16x32_bf16(pa[1], vf, oacc[1][dt], 0, 0, 0);
      }
    }
  }
  // --- write O (bf16) at [row, h*128 + d]
  unsigned short* ob = aout + (rb + w * 32) * 2048 + h * 128;
#pragma unroll
  for (int m = 0; m < 2; ++m)
#pragma unroll
    for (int dt = 0; dt < 8; ++dt)
#pragma unroll
      for (int r = 0; r < 4; ++r)
        ob[(long)(m * 16 + lq * 4 + r) * 2048 + dt * 16 + lr] = f2bf(oacc[m][dt][r]);
}

// ---------------- launch ----------------
extern "C" void kernel_launch(void* const* d_in, const int* in_sizes, int n_in,
                              void* d_out, int out_size, void* d_ws, size_t ws_size,
                              hipStream_t stream) {
  const float* x     = (const float*)d_in[0];
  const float* Wqkv  = (const float*)d_in[1];
  const float* b_qkv = (const float*)d_in[2];
  const float* Wout  = (const float*)d_in[3];
  const float* b_out = (const float*)d_in[4];
  float* out = (float*)d_out;

  char* ws = (char*)d_ws;
  // workspace layout (160 MiB total); aout aliases xs (xs dead after GEMM1)
  unsigned short* xs   = (unsigned short*)(ws);                 // 33,554,432 B
  unsigned short* aout = xs;                                    // alias
  unsigned short* wq   = (unsigned short*)(ws + 33554432);      // 25,165,824 B
  unsigned short* wo   = (unsigned short*)(ws + 58720256);      //  8,388,608 B
  unsigned short* qkv  = (unsigned short*)(ws + 67108864);      // 100,663,296 B

  k_gather<<<16384, 256, 0, stream>>>(x, xs);
  k_cast<<<12288, 256, 0, stream>>>(Wqkv, wq, 3145728);
  k_cast<<<4096, 256, 0, stream>>>(Wout, wo, 1048576);
  // QKV projection: [8192,2048] x [6144,2048]^T -> bf16 [8192,6144]
  k_gemm<true><<<32 * 24, 512, 0, stream>>>(xs, wq, b_qkv, (void*)qkv, 6144, 2048);
  // 512 fused attentions
  k_attn<<<512, 512, 0, stream>>>(qkv, aout);
  // out projection: [8192,2048] x [2048,2048]^T -> f32 d_out
  k_gemm<false><<<32 * 8, 512, 0, stream>>>(aout, wo, b_out, (void*)out, 2048, 2048);
}

// Round 8
// 341.062 us; speedup vs baseline: 1.1087x; 1.0388x over previous
//
#include <hip/hip_runtime.h>
#include <hip/hip_bf16.h>
#include <stdint.h>

#define DEVI __device__ __forceinline__

typedef __attribute__((ext_vector_type(8))) short bf16x8;   // 8 bf16 (4 VGPRs)
typedef __attribute__((ext_vector_type(4))) float f32x4;    // 4 fp32 acc

// Problem constants: B=2, S=8192, D=2048, H=16, hd=128, SEG=512, DIL=2
//   -> n_seg=16, L=256, M = B*16*256 = 8192 rows, E3 = 6144.

DEVI unsigned short f2bf(float f) {               // RNE float->bf16
  unsigned int u = __float_as_uint(f);
  return (unsigned short)((u + 0x7fffu + ((u >> 16) & 1u)) >> 16);
}

DEVI void load_lds16(const void* g, void* l) {    // async global->LDS, 16B/lane
  __builtin_amdgcn_global_load_lds(
      (const __attribute__((address_space(1))) unsigned int*)g,
      (__attribute__((address_space(3))) unsigned int*)l, 16, 0, 0);
}

DEVI bf16x8 ld8(const unsigned short* p) {
  return *reinterpret_cast<const bf16x8*>(p);
}

// ---------------- fused prep: dilated gather + both weight casts ----------
__global__ void k_prep(const float* __restrict__ x, unsigned short* __restrict__ xs,
                       const float* __restrict__ Wqkv, unsigned short* __restrict__ wq,
                       const float* __restrict__ Wout, unsigned short* __restrict__ wo) {
  const int bid = blockIdx.x;
  const float* src;
  unsigned short* dst;
  long i;
  if (bid < 16384) {                           // dilated gather + cast
    int ii = bid * 256 + threadIdx.x;          // 4,194,304 float4 items
    int r = ii >> 9;
    int c = (ii & 511) << 2;
    int b = r >> 12;
    int rem = r & 4095;
    int seg = rem >> 8;
    int lcl = rem & 255;
    long src_row = (long)b * 8192 + seg * 512 + lcl * 2;   // dilation=2
    const float4 v = *reinterpret_cast<const float4*>(x + src_row * 2048 + c);
    uint2 o;
    o.x = f2bf(v.x) | ((unsigned)f2bf(v.y) << 16);
    o.y = f2bf(v.z) | ((unsigned)f2bf(v.w) << 16);
    *reinterpret_cast<uint2*>(xs + (long)r * 2048 + c) = o;
    return;
  } else if (bid < 28672) {                    // Wqkv cast: 3,145,728 float4
    i = (long)(bid - 16384) * 256 + threadIdx.x;
    src = Wqkv; dst = wq;
  } else {                                     // Wout cast: 1,048,576 float4
    i = (long)(bid - 28672) * 256 + threadIdx.x;
    src = Wout; dst = wo;
  }
  const float4 v = *reinterpret_cast<const float4*>(src + i * 4);
  uint2 o;
  o.x = f2bf(v.x) | ((unsigned)f2bf(v.y) << 16);
  o.y = f2bf(v.z) | ((unsigned)f2bf(v.w) << 16);
  *reinterpret_cast<uint2*>(dst + i * 4) = o;
}

// ---------------- GEMM: C[M,N] = A[M,K] * B[N,K]^T + bias ----------------
// 256x256 tile, 8 waves (2M x 4N, 128x64 each). K in halves of 32; LDS ring
// of 4 slots x 32KB. DEPTH-3 pipeline: while computing half h, stage half
// h+3 (A piece in phase alpha, B piece in beta); trailing vmcnt(8) drains
// half h+1 only (h+2,h+3 stay in flight; issue->wait slack ~2 halves).
// Per half, 2 phases: {ds_read frags | stage piece | barrier | lgkmcnt(0) |
// setprio(1) 16 MFMA setprio(0) | barrier}.
// LDS layout: pair-packed 128B rows (0 bank conflicts, round-3-verified):
// prow=r>>1, c8=(r&1)*4+(k>>3), swizzled cs8=c8^(prow&7); inverse swizzle
// folded into per-lane global source (gload_lds rule).
// Block->tile mapping: XCD x (= blockIdx%8) owns a CHY x CHX rectangle of
// (by,bx) tiles (bijective), shrinking the per-XCD concurrent L2 working set.
// Epilogue: per-wave LDS transpose -> coalesced b128 stores.

DEVI void stage_piece(const unsigned short* gb, int K, int h, int op,
                      unsigned short* smem, int t, int w) {
  char* base = (char*)(smem + (h & 3) * 16384 + op * 8192);
#pragma unroll
  for (int i = 0; i < 2; ++i) {
    int s = i * 512 + t;                       // 16B slot 0..1023
    int prow = s >> 3;                         // 0..127
    int cs8 = s & 7;
    int c8 = cs8 ^ (prow & 7);
    int r = prow * 2 + (c8 >> 2);              // logical row 0..255
    int k0 = (c8 & 3) << 3;                    // k element 0/8/16/24
    load_lds16(gb + (long)r * K + h * 32 + k0, base + i * 8192 + w * 1024);
  }
}

#define FRAG_A(dst, mm)                                                      \
  { int r_ = wm * 128 + (mm) * 16 + lr;                                      \
    int p_ = r_ >> 1;                                                        \
    int cs_ = (((r_ & 1) << 2) | lq) ^ (p_ & 7);                             \
    dst = ld8(Ab_ + p_ * 64 + cs_ * 8); }
#define FRAG_B(dst, nn)                                                      \
  { int r_ = wn * 64 + (nn) * 16 + lr;                                       \
    int p_ = r_ >> 1;                                                        \
    int cs_ = (((r_ & 1) << 2) | lq) ^ (p_ & 7);                             \
    dst = ld8(Bb_ + p_ * 64 + cs_ * 8); }
#define MM(mm, areg)                                                         \
  acc[mm][0] = __builtin_amdgcn_mfma_f32_16x16x32_bf16(areg, bf0, acc[mm][0], 0, 0, 0); \
  acc[mm][1] = __builtin_amdgcn_mfma_f32_16x16x32_bf16(areg, bf1, acc[mm][1], 0, 0, 0); \
  acc[mm][2] = __builtin_amdgcn_mfma_f32_16x16x32_bf16(areg, bf2, acc[mm][2], 0, 0, 0); \
  acc[mm][3] = __builtin_amdgcn_mfma_f32_16x16x32_bf16(areg, bf3, acc[mm][3], 0, 0, 0);

// One K-half (32 wide): phase alpha computes m0-3 x n0-3, beta m4-7 x n0-3.
// DOSTAGE stages half h+3; VMLIT is the trailing counted wait.
#define HALF(HEXPR, DOSTAGE, VMLIT)                                          \
  {                                                                          \
    const int h_ = (HEXPR);                                                  \
    const unsigned short* Ab_ = smem + (h_ & 3) * 16384;                     \
    const unsigned short* Bb_ = Ab_ + 8192;                                  \
    bf16x8 af0, af1, af2, af3, bf0, bf1, bf2, bf3;                           \
    FRAG_B(bf0, 0) FRAG_B(bf1, 1) FRAG_B(bf2, 2) FRAG_B(bf3, 3)              \
    FRAG_A(af0, 0) FRAG_A(af1, 1) FRAG_A(af2, 2) FRAG_A(af3, 3)              \
    if (DOSTAGE) stage_piece(Agb, K, h_ + 3, 0, smem, t, w);                 \
    __builtin_amdgcn_s_barrier();                                            \
    asm volatile("s_waitcnt lgkmcnt(0)" ::: "memory");                       \
    __builtin_amdgcn_sched_barrier(0);                                       \
    __builtin_amdgcn_s_setprio(1);                                           \
    MM(0, af0) MM(1, af1) MM(2, af2) MM(3, af3)                              \
    __builtin_amdgcn_s_setprio(0);                                           \
    __builtin_amdgcn_s_barrier();                                            \
    FRAG_A(af0, 4) FRAG_A(af1, 5) FRAG_A(af2, 6) FRAG_A(af3, 7)              \
    if (DOSTAGE) stage_piece(Bgb, K, h_ + 3, 1, smem, t, w);                 \
    __builtin_amdgcn_s_barrier();                                            \
    asm volatile("s_waitcnt lgkmcnt(0)" ::: "memory");                       \
    __builtin_amdgcn_sched_barrier(0);                                       \
    __builtin_amdgcn_s_setprio(1);                                           \
    MM(4, af0) MM(5, af1) MM(6, af2) MM(7, af3)                              \
    __builtin_amdgcn_s_setprio(0);                                           \
    asm volatile("s_waitcnt vmcnt(" VMLIT ")" ::: "memory");                 \
    __builtin_amdgcn_s_barrier();                                            \
  }

template <bool BF16_OUT>
__global__ __launch_bounds__(512, 1)
void k_gemm(const unsigned short* __restrict__ A, const unsigned short* __restrict__ B,
            const float* __restrict__ bias, void* __restrict__ Cv, int N, int K,
            int CHY, int CHX) {
  __shared__ unsigned short smem[65536];       // 128 KB: 4 slots x 32KB
  const int nbx = N >> 8;
  // XCD-rectangular block mapping (bijective): XCD = blockIdx%8 owns a
  // CHY x CHX rect of (by,bx); local index walks it bx-minor.
  const int xcd = blockIdx.x & 7;
  const int local = blockIdx.x >> 3;
  const int nchx = nbx / CHX;
  const int by = (xcd / nchx) * CHY + local / CHX;
  const int bx = (xcd % nchx) * CHX + local % CHX;
  const int t = threadIdx.x, w = t >> 6, l = t & 63;
  const int lr = l & 15, lq = l >> 4;
  const int wm = w >> 2, wn = w & 3;
  const unsigned short* Agb = A + (long)by * 256 * K;
  const unsigned short* Bgb = B + (long)bx * 256 * K;
  const int nh = K >> 5;                       // 64 halves for K=2048
  f32x4 acc[8][4] = {};

  // prologue: stage halves 0,1,2 (12 loads/thread); vmcnt(8) drains half 0
  stage_piece(Agb, K, 0, 0, smem, t, w);
  stage_piece(Bgb, K, 0, 1, smem, t, w);
  stage_piece(Agb, K, 1, 0, smem, t, w);
  stage_piece(Bgb, K, 1, 1, smem, t, w);
  stage_piece(Agb, K, 2, 0, smem, t, w);
  stage_piece(Bgb, K, 2, 1, smem, t, w);
  asm volatile("s_waitcnt vmcnt(8)" ::: "memory");
  __builtin_amdgcn_s_barrier();

  // main loop: depth-3; trailing vmcnt(8) drains h+1, keeps h+2/h+3 in flight
  for (int h = 0; h < nh - 3; ++h) HALF(h, true, "8")
  HALF(nh - 3, false, "4")
  HALF(nh - 2, false, "0")
  HALF(nh - 1, false, "0")

  // ---- epilogue: per-wave LDS transpose -> coalesced b128 stores ----
  const long crow0 = (long)by * 256 + wm * 128;
  const int ccol0 = bx * 256 + wn * 64;
  float bv[4];
#pragma unroll
  for (int n = 0; n < 4; ++n) bv[n] = bias[ccol0 + n * 16 + lr];
  const int lrr = l >> 2;                      // 0..15 readback row
  if (BF16_OUT) {
    unsigned short* Lw = smem + w * 1216;      // 16 rows x stride 76 bf16
    const int lcb = (l & 3) * 8;
#pragma unroll
    for (int m = 0; m < 8; ++m) {
#pragma unroll
      for (int n = 0; n < 4; ++n)
#pragma unroll
        for (int r = 0; r < 4; ++r)
          Lw[(lq * 4 + r) * 76 + n * 16 + lr] = f2bf(acc[m][n][r] + bv[n]);
      asm volatile("s_waitcnt lgkmcnt(0)" ::: "memory");
#pragma unroll
      for (int rd = 0; rd < 2; ++rd) {
        bf16x8 v = ld8(Lw + lrr * 76 + lcb + rd * 32);
        *reinterpret_cast<bf16x8*>((unsigned short*)Cv +
            (crow0 + m * 16 + lrr) * N + ccol0 + lcb + rd * 32) = v;
      }
    }
  } else {
    float* Lf = (float*)smem + w * 1216;       // 16 rows x stride 76 f32
    const int lcf = (l & 3) * 4;
#pragma unroll
    for (int m = 0; m < 8; ++m) {
#pragma unroll
      for (int n = 0; n < 4; ++n)
#pragma unroll
        for (int r = 0; r < 4; ++r)
          Lf[(lq * 4 + r) * 76 + n * 16 + lr] = acc[m][n][r] + bv[n];
      asm volatile("s_waitcnt lgkmcnt(0)" ::: "memory");
#pragma unroll
      for (int rd = 0; rd < 4; ++rd) {
        float4 v = *reinterpret_cast<const float4*>(Lf + lrr * 76 + lcf + rd * 16);
        *reinterpret_cast<float4*>((float*)Cv +
            (crow0 + m * 16 + lrr) * N + ccol0 + lcf + rd * 16) = v;
      }
    }
  }
}

// ---------------- fused per-(b,n,h) attention ----------------
// 1 block = 1 (b,n,h): 8 waves x 32 q-rows. K,Vt staged in LDS (swizzled),
// full 256-wide scores per wave in registers, wave-parallel softmax,
// P -> per-wave LDS region (reusing K space) -> PV MFMA.
__global__ __launch_bounds__(512)
void k_attn(const unsigned short* __restrict__ qkv, unsigned short* __restrict__ aout) {
  __shared__ unsigned short smem[65536];    // 128KB
  unsigned short* Kl = smem;                // [256][128] bf16, chunk ^= row&7; reused as P
  unsigned short* Vt = smem + 32768;        // [128][256] bf16 (d-major), chunk ^= (d^(d>>3))&7
  const int p = blockIdx.x;
  const int h = p & 15;
  const long rb = (long)(p >> 4) * 256;
  const int t = threadIdx.x, w = t >> 6, l = t & 63;
  const int lr = l & 15, lq = l >> 4;

  // --- stage K via global_load_lds with pre-swizzled source
  const unsigned short* kb = qkv + rb * 6144 + 2048 + h * 128;
#pragma unroll
  for (int i = 0; i < 8; ++i) {
    int s = i * 512 + t;
    int row = s >> 4;
    int ch = (s & 15) ^ (row & 7);
    load_lds16(kb + (long)row * 6144 + ch * 8, (char*)Kl + i * 8192 + w * 1024);
  }
  // --- stage V transposed (reg path; swizzled scatter writes, ~2-way conflicts)
  const unsigned short* vb = qkv + rb * 6144 + 4096 + h * 128;
#pragma unroll
  for (int j0 = 0; j0 < 8; ++j0) {
    int k = j0 * 32 + (t >> 4);
    int d0 = (t & 15) * 8;
    bf16x8 v = ld8(vb + (long)k * 6144 + d0);
#pragma unroll
    for (int j = 0; j < 8; ++j) {
      int d = d0 + j;
      int ch = (k >> 3) ^ ((d ^ (d >> 3)) & 7);
      Vt[d * 256 + ch * 8 + (k & 7)] = (unsigned short)(short)v[j];
    }
  }
  // --- Q fragments straight from global
  const unsigned short* qb = qkv + (rb + w * 32) * 6144 + h * 128;
  bf16x8 qa[2][4];
#pragma unroll
  for (int m = 0; m < 2; ++m)
#pragma unroll
    for (int kt = 0; kt < 4; ++kt)
      qa[m][kt] = ld8(qb + (long)(m * 16 + lr) * 6144 + kt * 32 + lq * 8);

  __syncthreads();

  // --- S = Q K^T : per wave 32x256 in registers
  f32x4 sacc[2][16] = {};
#pragma unroll
  for (int n = 0; n < 16; ++n) {
    int row = n * 16 + lr;
#pragma unroll
    for (int kt = 0; kt < 4; ++kt) {
      int ch = (kt * 4 + lq) ^ (row & 7);
      bf16x8 kf = ld8(Kl + row * 128 + ch * 8);
      sacc[0][n] = __builtin_amdgcn_mfma_f32_16x16x32_bf16(qa[0][kt], kf, sacc[0][n], 0, 0, 0);
      sacc[1][n] = __builtin_amdgcn_mfma_f32_16x16x32_bf16(qa[1][kt], kf, sacc[1][n], 0, 0, 0);
    }
  }
  // --- softmax(scale*S) rowwise; row = m*16+lq*4+r, col spread over n and lane&15
  const float scale = 0.08838834764831845f;  // 1/sqrt(128)
  float mx[2][4], sm[2][4];
#pragma unroll
  for (int m = 0; m < 2; ++m)
#pragma unroll
    for (int r = 0; r < 4; ++r) {
      float v = sacc[m][0][r];
#pragma unroll
      for (int n = 1; n < 16; ++n) v = fmaxf(v, sacc[m][n][r]);
      mx[m][r] = v;
      sm[m][r] = 0.f;
    }
#pragma unroll
  for (int mk = 1; mk < 16; mk <<= 1)
#pragma unroll
    for (int m = 0; m < 2; ++m)
#pragma unroll
      for (int r = 0; r < 4; ++r)
        mx[m][r] = fmaxf(mx[m][r], __shfl_xor(mx[m][r], mk));
#pragma unroll
  for (int m = 0; m < 2; ++m)
#pragma unroll
    for (int n = 0; n < 16; ++n)
#pragma unroll
      for (int r = 0; r < 4; ++r) {
        float e = __expf((sacc[m][n][r] - mx[m][r]) * scale);
        sacc[m][n][r] = e;
        sm[m][r] += e;
      }
#pragma unroll
  for (int mk = 1; mk < 16; mk <<= 1)
#pragma unroll
    for (int m = 0; m < 2; ++m)
#pragma unroll
      for (int r = 0; r < 4; ++r)
        sm[m][r] += __shfl_xor(sm[m][r], mk);
  float ri[2][4];
#pragma unroll
  for (int m = 0; m < 2; ++m)
#pragma unroll
    for (int r = 0; r < 4; ++r) ri[m][r] = 1.0f / sm[m][r];

  // --- normalize + pack P to bf16 pairs (frees the 128 f32 sacc regs)
  unsigned int pb[2][16][2];
#pragma unroll
  for (int m = 0; m < 2; ++m)
#pragma unroll
    for (int n = 0; n < 16; ++n) {
      pb[m][n][0] = f2bf(sacc[m][n][0] * ri[m][0]) | ((unsigned)f2bf(sacc[m][n][1] * ri[m][1]) << 16);
      pb[m][n][1] = f2bf(sacc[m][n][2] * ri[m][2]) | ((unsigned)f2bf(sacc[m][n][3] * ri[m][3]) << 16);
    }

  __syncthreads();                       // all waves done reading Kl -> reuse as P
  unsigned short* Pl = Kl + w * 4096;    // per-wave 8KB: [32][128] bf16, chunk ^= row&7
  f32x4 oacc[2][8] = {};
#pragma unroll
  for (int half = 0; half < 2; ++half) {
#pragma unroll
    for (int m = 0; m < 2; ++m)
#pragma unroll
      for (int n = 0; n < 8; ++n) {
        int col = n * 16 + lr;
        int row0 = m * 16 + lq * 4;
#pragma unroll
        for (int pr = 0; pr < 2; ++pr) {
          unsigned int u = pb[m][half * 8 + n][pr];
          int ra = row0 + pr * 2, rbw = ra + 1;
          int ca = (col >> 3) ^ (ra & 7);
          int cb = (col >> 3) ^ (rbw & 7);
          Pl[ra * 128 + ca * 8 + (col & 7)] = (unsigned short)(u & 0xffffu);
          Pl[rbw * 128 + cb * 8 + (col & 7)] = (unsigned short)(u >> 16);
        }
      }
    // O += P V  (A-frags from Pl, B-frags from swizzled Vt)
#pragma unroll
    for (int kt = 0; kt < 4; ++kt) {
      bf16x8 pa[2];
#pragma unroll
      for (int m = 0; m < 2; ++m) {
        int row = m * 16 + lr;
        int ch = (kt * 4 + lq) ^ (row & 7);
        pa[m] = ld8(Pl + row * 128 + ch * 8);
      }
#pragma unroll
      for (int dt = 0; dt < 8; ++dt) {
        int d = dt * 16 + lr;
        int kg = half * 128 + kt * 32 + lq * 8;
        int ch = (kg >> 3) ^ ((d ^ (d >> 3)) & 7);
        bf16x8 vf = ld8(Vt + d * 256 + ch * 8);
        oacc[0][dt] = __builtin_amdgcn_mfma_f32_16x16x32_bf16(pa[0], vf, oacc[0][dt], 0, 0, 0);
        oacc[1][dt] = __builtin_amdgcn_mfma_f32_16x16x32_bf16(pa[1], vf, oacc[1][dt], 0, 0, 0);
      }
    }
  }
  // --- write O (bf16) at [row, h*128 + d]
  unsigned short* ob = aout + (rb + w * 32) * 2048 + h * 128;
#pragma unroll
  for (int m = 0; m < 2; ++m)
#pragma unroll
    for (int dt = 0; dt < 8; ++dt)
#pragma unroll
      for (int r = 0; r < 4; ++r)
        ob[(long)(m * 16 + lq * 4 + r) * 2048 + dt * 16 + lr] = f2bf(oacc[m][dt][r]);
}

// ---------------- launch ----------------
extern "C" void kernel_launch(void* const* d_in, const int* in_sizes, int n_in,
                              void* d_out, int out_size, void* d_ws, size_t ws_size,
                              hipStream_t stream) {
  const float* x     = (const float*)d_in[0];
  const float* Wqkv  = (const float*)d_in[1];
  const float* b_qkv = (const float*)d_in[2];
  const float* Wout  = (const float*)d_in[3];
  const float* b_out = (const float*)d_in[4];
  float* out = (float*)d_out;

  char* ws = (char*)d_ws;
  // workspace layout (160 MiB total); aout aliases xs (xs dead after GEMM1)
  unsigned short* xs   = (unsigned short*)(ws);                 // 33,554,432 B
  unsigned short* aout = xs;                                    // alias
  unsigned short* wq   = (unsigned short*)(ws + 33554432);      // 25,165,824 B
  unsigned short* wo   = (unsigned short*)(ws + 58720256);      //  8,388,608 B
  unsigned short* qkv  = (unsigned short*)(ws + 67108864);      // 100,663,296 B

  // fused prep: gather (16384 blocks) + Wqkv cast (12288) + Wout cast (4096)
  k_prep<<<32768, 256, 0, stream>>>(x, xs, Wqkv, wq, Wout, wo);
  // QKV projection: [8192,2048] x [6144,2048]^T -> bf16 [8192,6144]
  // grid 32x24=768; XCD rect 16(by) x 6(bx)
  k_gemm<true><<<768, 512, 0, stream>>>(xs, wq, b_qkv, (void*)qkv, 6144, 2048, 16, 6);
  // 512 fused attentions
  k_attn<<<512, 512, 0, stream>>>(qkv, aout);
  // out projection: [8192,2048] x [2048,2048]^T -> f32 d_out
  // grid 32x8=256; XCD rect 8(by) x 4(bx)
  k_gemm<false><<<256, 512, 0, stream>>>(aout, wo, b_out, (void*)out, 2048, 2048, 8, 4);
}

// Round 9
// 332.870 us; speedup vs baseline: 1.1360x; 1.0246x over previous
//
#include <hip/hip_runtime.h>
#include <hip/hip_bf16.h>
#include <stdint.h>

#define DEVI __device__ __forceinline__

typedef __attribute__((ext_vector_type(8))) short bf16x8;   // 8 bf16 (4 VGPRs)
typedef __attribute__((ext_vector_type(4))) float f32x4;    // 4 fp32 acc

// Problem constants: B=2, S=8192, D=2048, H=16, hd=128, SEG=512, DIL=2
//   -> n_seg=16, L=256, M = B*16*256 = 8192 rows, E3 = 6144.

DEVI unsigned short f2bf(float f) {               // RNE float->bf16
  unsigned int u = __float_as_uint(f);
  return (unsigned short)((u + 0x7fffu + ((u >> 16) & 1u)) >> 16);
}

DEVI void load_lds16(const void* g, void* l) {    // async global->LDS, 16B/lane
  __builtin_amdgcn_global_load_lds(
      (const __attribute__((address_space(1))) unsigned int*)g,
      (__attribute__((address_space(3))) unsigned int*)l, 16, 0, 0);
}

DEVI bf16x8 ld8(const unsigned short* p) {
  return *reinterpret_cast<const bf16x8*>(p);
}

// ---------------- fused prep: dilated gather + both weight casts ----------
__global__ void k_prep(const float* __restrict__ x, unsigned short* __restrict__ xs,
                       const float* __restrict__ Wqkv, unsigned short* __restrict__ wq,
                       const float* __restrict__ Wout, unsigned short* __restrict__ wo) {
  const int bid = blockIdx.x;
  const float* src;
  unsigned short* dst;
  long i;
  if (bid < 16384) {                           // dilated gather + cast
    int ii = bid * 256 + threadIdx.x;          // 4,194,304 float4 items
    int r = ii >> 9;
    int c = (ii & 511) << 2;
    int b = r >> 12;
    int rem = r & 4095;
    int seg = rem >> 8;
    int lcl = rem & 255;
    long src_row = (long)b * 8192 + seg * 512 + lcl * 2;   // dilation=2
    const float4 v = *reinterpret_cast<const float4*>(x + src_row * 2048 + c);
    uint2 o;
    o.x = f2bf(v.x) | ((unsigned)f2bf(v.y) << 16);
    o.y = f2bf(v.z) | ((unsigned)f2bf(v.w) << 16);
    *reinterpret_cast<uint2*>(xs + (long)r * 2048 + c) = o;
    return;
  } else if (bid < 28672) {                    // Wqkv cast: 3,145,728 float4
    i = (long)(bid - 16384) * 256 + threadIdx.x;
    src = Wqkv; dst = wq;
  } else {                                     // Wout cast: 1,048,576 float4
    i = (long)(bid - 28672) * 256 + threadIdx.x;
    src = Wout; dst = wo;
  }
  const float4 v = *reinterpret_cast<const float4*>(src + i * 4);
  uint2 o;
  o.x = f2bf(v.x) | ((unsigned)f2bf(v.y) << 16);
  o.y = f2bf(v.z) | ((unsigned)f2bf(v.w) << 16);
  *reinterpret_cast<uint2*>(dst + i * 4) = o;
}

// ---------------- GEMM: C[M,N] = A[M,K] * B[N,K]^T + bias ----------------
// 256x256 tile, 8 waves (2M x 4N, 128x64 each). K in halves of 32; LDS ring
// of 4 slots x 32KB. DEPTH-3 pipeline: while computing half h, stage half
// h+3; trailing vmcnt(8) drains half h+1 only; ONE barrier per half.
// NO intra-half barriers: the half-entry barrier already guarantees slot h
// is fully populated (all waves' vmcnt drained h's loads before it) and all
// WAR slot-reuse hazards (ring-4, depth-3) are ordered by the same barrier.
// Within a half the compiler freely interleaves the 12 frag ds_reads with
// the 32 MFMA (fine-grained lgkmcnt), and waves drift so one wave's LDS
// reads overlap the other wave's MFMA -> cross-pipe overlap (the missing
// ~50% in rounds 2-8, which ran LDS and MFMA additively in lockstep).
// LDS layout: pair-packed 128B rows (0 bank conflicts, round-3-verified):
// prow=r>>1, c8=(r&1)*4+(k>>3), swizzled cs8=c8^(prow&7); inverse swizzle
// folded into per-lane global source (gload_lds rule).
// Block->tile mapping: XCD (= blockIdx%8) owns a CHY x CHX rectangle of
// (by,bx) tiles (bijective) -> small per-XCD L2 set (round-8: FETCH -54%).
// Epilogue: per-wave LDS transpose -> coalesced b128 stores.

DEVI void stage_piece(const unsigned short* gb, int K, int h, int op,
                      unsigned short* smem, int t, int w) {
  char* base = (char*)(smem + (h & 3) * 16384 + op * 8192);
#pragma unroll
  for (int i = 0; i < 2; ++i) {
    int s = i * 512 + t;                       // 16B slot 0..1023
    int prow = s >> 3;                         // 0..127
    int cs8 = s & 7;
    int c8 = cs8 ^ (prow & 7);
    int r = prow * 2 + (c8 >> 2);              // logical row 0..255
    int k0 = (c8 & 3) << 3;                    // k element 0/8/16/24
    load_lds16(gb + (long)r * K + h * 32 + k0, base + i * 8192 + w * 1024);
  }
}

#define FRAG_A(dst, mm)                                                      \
  { int r_ = wm * 128 + (mm) * 16 + lr;                                      \
    int p_ = r_ >> 1;                                                        \
    int cs_ = (((r_ & 1) << 2) | lq) ^ (p_ & 7);                             \
    dst = ld8(Ab_ + p_ * 64 + cs_ * 8); }
#define FRAG_B(dst, nn)                                                      \
  { int r_ = wn * 64 + (nn) * 16 + lr;                                       \
    int p_ = r_ >> 1;                                                        \
    int cs_ = (((r_ & 1) << 2) | lq) ^ (p_ & 7);                             \
    dst = ld8(Bb_ + p_ * 64 + cs_ * 8); }

// One K-half (32 wide): stage h+3, 12 frag reads, 32 MFMA (free-scheduled),
// trailing counted vmcnt + single barrier.
#define HALF(HEXPR, DOSTAGE, VMLIT)                                          \
  {                                                                          \
    const int h_ = (HEXPR);                                                  \
    const unsigned short* Ab_ = smem + (h_ & 3) * 16384;                     \
    const unsigned short* Bb_ = Ab_ + 8192;                                  \
    if (DOSTAGE) {                                                           \
      stage_piece(Agb, K, h_ + 3, 0, smem, t, w);                            \
      stage_piece(Bgb, K, h_ + 3, 1, smem, t, w);                            \
    }                                                                        \
    bf16x8 bfr[4], afr[8];                                                   \
    FRAG_B(bfr[0], 0) FRAG_B(bfr[1], 1) FRAG_B(bfr[2], 2) FRAG_B(bfr[3], 3)  \
    FRAG_A(afr[0], 0) FRAG_A(afr[1], 1) FRAG_A(afr[2], 2) FRAG_A(afr[3], 3)  \
    FRAG_A(afr[4], 4) FRAG_A(afr[5], 5) FRAG_A(afr[6], 6) FRAG_A(afr[7], 7)  \
    _Pragma("unroll")                                                        \
    for (int m_ = 0; m_ < 8; ++m_)                                           \
      _Pragma("unroll")                                                      \
      for (int n_ = 0; n_ < 4; ++n_)                                         \
        acc[m_][n_] = __builtin_amdgcn_mfma_f32_16x16x32_bf16(               \
            afr[m_], bfr[n_], acc[m_][n_], 0, 0, 0);                         \
    asm volatile("s_waitcnt vmcnt(" VMLIT ")" ::: "memory");                 \
    __builtin_amdgcn_s_barrier();                                            \
    asm volatile("" ::: "memory");                                           \
  }

template <bool BF16_OUT>
__global__ __launch_bounds__(512, 1)
void k_gemm(const unsigned short* __restrict__ A, const unsigned short* __restrict__ B,
            const float* __restrict__ bias, void* __restrict__ Cv, int N, int K,
            int CHY, int CHX) {
  __shared__ unsigned short smem[65536];       // 128 KB: 4 slots x 32KB
  const int nbx = N >> 8;
  // XCD-rectangular block mapping (bijective): XCD = blockIdx%8 owns a
  // CHY x CHX rect of (by,bx); local index walks it bx-minor.
  const int xcd = blockIdx.x & 7;
  const int local = blockIdx.x >> 3;
  const int nchx = nbx / CHX;
  const int by = (xcd / nchx) * CHY + local / CHX;
  const int bx = (xcd % nchx) * CHX + local % CHX;
  const int t = threadIdx.x, w = t >> 6, l = t & 63;
  const int lr = l & 15, lq = l >> 4;
  const int wm = w >> 2, wn = w & 3;
  const unsigned short* Agb = A + (long)by * 256 * K;
  const unsigned short* Bgb = B + (long)bx * 256 * K;
  const int nh = K >> 5;                       // 64 halves for K=2048
  f32x4 acc[8][4] = {};

  // prologue: stage halves 0,1,2 (12 loads/thread); vmcnt(8) drains half 0
  stage_piece(Agb, K, 0, 0, smem, t, w);
  stage_piece(Bgb, K, 0, 1, smem, t, w);
  stage_piece(Agb, K, 1, 0, smem, t, w);
  stage_piece(Bgb, K, 1, 1, smem, t, w);
  stage_piece(Agb, K, 2, 0, smem, t, w);
  stage_piece(Bgb, K, 2, 1, smem, t, w);
  asm volatile("s_waitcnt vmcnt(8)" ::: "memory");
  __builtin_amdgcn_s_barrier();
  asm volatile("" ::: "memory");

  // main loop: depth-3; trailing vmcnt(8) drains h+1, keeps h+2/h+3 in flight
  for (int h = 0; h < nh - 3; ++h) HALF(h, true, "8")
  HALF(nh - 3, false, "4")
  HALF(nh - 2, false, "0")
  HALF(nh - 1, false, "0")

  // ---- epilogue: per-wave LDS transpose -> coalesced b128 stores ----
  const long crow0 = (long)by * 256 + wm * 128;
  const int ccol0 = bx * 256 + wn * 64;
  float bv[4];
#pragma unroll
  for (int n = 0; n < 4; ++n) bv[n] = bias[ccol0 + n * 16 + lr];
  const int lrr = l >> 2;                      // 0..15 readback row
  if (BF16_OUT) {
    unsigned short* Lw = smem + w * 1216;      // 16 rows x stride 76 bf16
    const int lcb = (l & 3) * 8;
#pragma unroll
    for (int m = 0; m < 8; ++m) {
#pragma unroll
      for (int n = 0; n < 4; ++n)
#pragma unroll
        for (int r = 0; r < 4; ++r)
          Lw[(lq * 4 + r) * 76 + n * 16 + lr] = f2bf(acc[m][n][r] + bv[n]);
      asm volatile("s_waitcnt lgkmcnt(0)" ::: "memory");
#pragma unroll
      for (int rd = 0; rd < 2; ++rd) {
        bf16x8 v = ld8(Lw + lrr * 76 + lcb + rd * 32);
        *reinterpret_cast<bf16x8*>((unsigned short*)Cv +
            (crow0 + m * 16 + lrr) * N + ccol0 + lcb + rd * 32) = v;
      }
    }
  } else {
    float* Lf = (float*)smem + w * 1216;       // 16 rows x stride 76 f32
    const int lcf = (l & 3) * 4;
#pragma unroll
    for (int m = 0; m < 8; ++m) {
#pragma unroll
      for (int n = 0; n < 4; ++n)
#pragma unroll
        for (int r = 0; r < 4; ++r)
          Lf[(lq * 4 + r) * 76 + n * 16 + lr] = acc[m][n][r] + bv[n];
      asm volatile("s_waitcnt lgkmcnt(0)" ::: "memory");
#pragma unroll
      for (int rd = 0; rd < 4; ++rd) {
        float4 v = *reinterpret_cast<const float4*>(Lf + lrr * 76 + lcf + rd * 16);
        *reinterpret_cast<float4*>((float*)Cv +
            (crow0 + m * 16 + lrr) * N + ccol0 + lcf + rd * 16) = v;
      }
    }
  }
}

// ---------------- fused per-(b,n,h) attention ----------------
// 1 block = 1 (b,n,h): 8 waves x 32 q-rows. K,Vt staged in LDS (swizzled),
// full 256-wide scores per wave in registers, wave-parallel softmax,
// P -> per-wave LDS region (reusing K space) -> PV MFMA.
__global__ __launch_bounds__(512)
void k_attn(const unsigned short* __restrict__ qkv, unsigned short* __restrict__ aout) {
  __shared__ unsigned short smem[65536];    // 128KB
  unsigned short* Kl = smem;                // [256][128] bf16, chunk ^= row&7; reused as P
  unsigned short* Vt = smem + 32768;        // [128][256] bf16 (d-major), chunk ^= (d^(d>>3))&7
  const int p = blockIdx.x;
  const int h = p & 15;
  const long rb = (long)(p >> 4) * 256;
  const int t = threadIdx.x, w = t >> 6, l = t & 63;
  const int lr = l & 15, lq = l >> 4;

  // --- stage K via global_load_lds with pre-swizzled source
  const unsigned short* kb = qkv + rb * 6144 + 2048 + h * 128;
#pragma unroll
  for (int i = 0; i < 8; ++i) {
    int s = i * 512 + t;
    int row = s >> 4;
    int ch = (s & 15) ^ (row & 7);
    load_lds16(kb + (long)row * 6144 + ch * 8, (char*)Kl + i * 8192 + w * 1024);
  }
  // --- stage V transposed (reg path; swizzled scatter writes, ~2-way conflicts)
  const unsigned short* vb = qkv + rb * 6144 + 4096 + h * 128;
#pragma unroll
  for (int j0 = 0; j0 < 8; ++j0) {
    int k = j0 * 32 + (t >> 4);
    int d0 = (t & 15) * 8;
    bf16x8 v = ld8(vb + (long)k * 6144 + d0);
#pragma unroll
    for (int j = 0; j < 8; ++j) {
      int d = d0 + j;
      int ch = (k >> 3) ^ ((d ^ (d >> 3)) & 7);
      Vt[d * 256 + ch * 8 + (k & 7)] = (unsigned short)(short)v[j];
    }
  }
  // --- Q fragments straight from global
  const unsigned short* qb = qkv + (rb + w * 32) * 6144 + h * 128;
  bf16x8 qa[2][4];
#pragma unroll
  for (int m = 0; m < 2; ++m)
#pragma unroll
    for (int kt = 0; kt < 4; ++kt)
      qa[m][kt] = ld8(qb + (long)(m * 16 + lr) * 6144 + kt * 32 + lq * 8);

  __syncthreads();

  // --- S = Q K^T : per wave 32x256 in registers
  f32x4 sacc[2][16] = {};
#pragma unroll
  for (int n = 0; n < 16; ++n) {
    int row = n * 16 + lr;
#pragma unroll
    for (int kt = 0; kt < 4; ++kt) {
      int ch = (kt * 4 + lq) ^ (row & 7);
      bf16x8 kf = ld8(Kl + row * 128 + ch * 8);
      sacc[0][n] = __builtin_amdgcn_mfma_f32_16x16x32_bf16(qa[0][kt], kf, sacc[0][n], 0, 0, 0);
      sacc[1][n] = __builtin_amdgcn_mfma_f32_16x16x32_bf16(qa[1][kt], kf, sacc[1][n], 0, 0, 0);
    }
  }
  // --- softmax(scale*S) rowwise; row = m*16+lq*4+r, col spread over n and lane&15
  const float scale = 0.08838834764831845f;  // 1/sqrt(128)
  float mx[2][4], sm[2][4];
#pragma unroll
  for (int m = 0; m < 2; ++m)
#pragma unroll
    for (int r = 0; r < 4; ++r) {
      float v = sacc[m][0][r];
#pragma unroll
      for (int n = 1; n < 16; ++n) v = fmaxf(v, sacc[m][n][r]);
      mx[m][r] = v;
      sm[m][r] = 0.f;
    }
#pragma unroll
  for (int mk = 1; mk < 16; mk <<= 1)
#pragma unroll
    for (int m = 0; m < 2; ++m)
#pragma unroll
      for (int r = 0; r < 4; ++r)
        mx[m][r] = fmaxf(mx[m][r], __shfl_xor(mx[m][r], mk));
#pragma unroll
  for (int m = 0; m < 2; ++m)
#pragma unroll
    for (int n = 0; n < 16; ++n)
#pragma unroll
      for (int r = 0; r < 4; ++r) {
        float e = __expf((sacc[m][n][r] - mx[m][r]) * scale);
        sacc[m][n][r] = e;
        sm[m][r] += e;
      }
#pragma unroll
  for (int mk = 1; mk < 16; mk <<= 1)
#pragma unroll
    for (int m = 0; m < 2; ++m)
#pragma unroll
      for (int r = 0; r < 4; ++r)
        sm[m][r] += __shfl_xor(sm[m][r], mk);
  float ri[2][4];
#pragma unroll
  for (int m = 0; m < 2; ++m)
#pragma unroll
    for (int r = 0; r < 4; ++r) ri[m][r] = 1.0f / sm[m][r];

  // --- normalize + pack P to bf16 pairs (frees the 128 f32 sacc regs)
  unsigned int pb[2][16][2];
#pragma unroll
  for (int m = 0; m < 2; ++m)
#pragma unroll
    for (int n = 0; n < 16; ++n) {
      pb[m][n][0] = f2bf(sacc[m][n][0] * ri[m][0]) | ((unsigned)f2bf(sacc[m][n][1] * ri[m][1]) << 16);
      pb[m][n][1] = f2bf(sacc[m][n][2] * ri[m][2]) | ((unsigned)f2bf(sacc[m][n][3] * ri[m][3]) << 16);
    }

  __syncthreads();                       // all waves done reading Kl -> reuse as P
  unsigned short* Pl = Kl + w * 4096;    // per-wave 8KB: [32][128] bf16, chunk ^= row&7
  f32x4 oacc[2][8] = {};
#pragma unroll
  for (int half = 0; half < 2; ++half) {
#pragma unroll
    for (int m = 0; m < 2; ++m)
#pragma unroll
      for (int n = 0; n < 8; ++n) {
        int col = n * 16 + lr;
        int row0 = m * 16 + lq * 4;
#pragma unroll
        for (int pr = 0; pr < 2; ++pr) {
          unsigned int u = pb[m][half * 8 + n][pr];
          int ra = row0 + pr * 2, rbw = ra + 1;
          int ca = (col >> 3) ^ (ra & 7);
          int cb = (col >> 3) ^ (rbw & 7);
          Pl[ra * 128 + ca * 8 + (col & 7)] = (unsigned short)(u & 0xffffu);
          Pl[rbw * 128 + cb * 8 + (col & 7)] = (unsigned short)(u >> 16);
        }
      }
    // O += P V  (A-frags from Pl, B-frags from swizzled Vt)
#pragma unroll
    for (int kt = 0; kt < 4; ++kt) {
      bf16x8 pa[2];
#pragma unroll
      for (int m = 0; m < 2; ++m) {
        int row = m * 16 + lr;
        int ch = (kt * 4 + lq) ^ (row & 7);
        pa[m] = ld8(Pl + row * 128 + ch * 8);
      }
#pragma unroll
      for (int dt = 0; dt < 8; ++dt) {
        int d = dt * 16 + lr;
        int kg = half * 128 + kt * 32 + lq * 8;
        int ch = (kg >> 3) ^ ((d ^ (d >> 3)) & 7);
        bf16x8 vf = ld8(Vt + d * 256 + ch * 8);
        oacc[0][dt] = __builtin_amdgcn_mfma_f32_16x16x32_bf16(pa[0], vf, oacc[0][dt], 0, 0, 0);
        oacc[1][dt] = __builtin_amdgcn_mfma_f32_16x16x32_bf16(pa[1], vf, oacc[1][dt], 0, 0, 0);
      }
    }
  }
  // --- write O (bf16) at [row, h*128 + d]
  unsigned short* ob = aout + (rb + w * 32) * 2048 + h * 128;
#pragma unroll
  for (int m = 0; m < 2; ++m)
#pragma unroll
    for (int dt = 0; dt < 8; ++dt)
#pragma unroll
      for (int r = 0; r < 4; ++r)
        ob[(long)(m * 16 + lq * 4 + r) * 2048 + dt * 16 + lr] = f2bf(oacc[m][dt][r]);
}

// ---------------- launch ----------------
extern "C" void kernel_launch(void* const* d_in, const int* in_sizes, int n_in,
                              void* d_out, int out_size, void* d_ws, size_t ws_size,
                              hipStream_t stream) {
  const float* x     = (const float*)d_in[0];
  const float* Wqkv  = (const float*)d_in[1];
  const float* b_qkv = (const float*)d_in[2];
  const float* Wout  = (const float*)d_in[3];
  const float* b_out = (const float*)d_in[4];
  float* out = (float*)d_out;

  char* ws = (char*)d_ws;
  // workspace layout (160 MiB total); aout aliases xs (xs dead after GEMM1)
  unsigned short* xs   = (unsigned short*)(ws);                 // 33,554,432 B
  unsigned short* aout = xs;                                    // alias
  unsigned short* wq   = (unsigned short*)(ws + 33554432);      // 25,165,824 B
  unsigned short* wo   = (unsigned short*)(ws + 58720256);      //  8,388,608 B
  unsigned short* qkv  = (unsigned short*)(ws + 67108864);      // 100,663,296 B

  // fused prep: gather (16384 blocks) + Wqkv cast (12288) + Wout cast (4096)
  k_prep<<<32768, 256, 0, stream>>>(x, xs, Wqkv, wq, Wout, wo);
  // QKV projection: [8192,2048] x [6144,2048]^T -> bf16 [8192,6144]
  // grid 32x24=768; XCD rect 16(by) x 6(bx)
  k_gemm<true><<<768, 512, 0, stream>>>(xs, wq, b_qkv, (void*)qkv, 6144, 2048, 16, 6);
  // 512 fused attentions
  k_attn<<<512, 512, 0, stream>>>(qkv, aout);
  // out projection: [8192,2048] x [2048,2048]^T -> f32 d_out
  // grid 32x8=256; XCD rect 8(by) x 4(bx)
  k_gemm<false><<<256, 512, 0, stream>>>(aout, wo, b_out, (void*)out, 2048, 2048, 8, 4);
}